// Round 24
// baseline (451.928 us; speedup 1.0000x reference)
//
#include <hip/hip_runtime.h>
#include <hip/hip_bf16.h>

typedef short bf16x8 __attribute__((ext_vector_type(8)));
typedef float f32x4 __attribute__((ext_vector_type(4)));
typedef unsigned short u16;

#define NTOK 2048
#define CDIM 2048
#define TSEQ 1024
#define NH   32
#define NKV  8
#define DH   128
#define NE   8
#define FDIM 768
#define CAP  2048

#define GLOAD_LDS16(g, l) \
  __builtin_amdgcn_global_load_lds((const __attribute__((address_space(1))) void*)(g), \
                                   (__attribute__((address_space(3))) void*)(l), 16, 0, 0)

__device__ __forceinline__ u16 f2bf(float f){
  union { float f; unsigned u; } v; v.f = f;
  unsigned r = v.u + 0x7FFFu + ((v.u >> 16) & 1u);
  return (u16)(r >> 16);
}
__device__ __forceinline__ float bf2f(u16 x){
  union { unsigned u; float f; } v; v.u = ((unsigned)x) << 16; return v.f;
}

__device__ __forceinline__ f32x4 mfma_bf16(bf16x8 a, bf16x8 b, f32x4 c){
  return __builtin_amdgcn_mfma_f32_16x16x32_bf16(a, b, c, 0, 0, 0);
}

// bijective XCD-chunk swizzle (m204): orig linear id -> chunked id
__device__ __forceinline__ int xcd_swz(int orig, int nwg){
  int xcd = orig & 7;
  int q = nwg >> 3, r = nwg & 7;
  int base = (xcd < r) ? xcd*(q+1) : r*(q+1) + (xcd-r)*q;
  return base + (orig >> 3);
}

// ---- fast transpose + fp32->bf16 cast, 64x64 tile: out[c][r] = in[r][c] -----------
__global__ void cast_transpose(const float* __restrict__ in, u16* __restrict__ out,
                               int R, int Cc, int rstride, int d1,
                               long long s_hi, long long s_lo)
{
  __shared__ u16 tile[64][72];
  int z = blockIdx.z;
  in  += (long long)(z / d1) * s_hi + (long long)(z % d1) * s_lo;
  out += (size_t)z * R * Cc;
  int r0 = blockIdx.y*64, c0 = blockIdx.x*64;
  int lr = threadIdx.x >> 4;          // 0..15
  int lc = (threadIdx.x & 15) * 4;    // 0..60
  #pragma unroll
  for(int i=0;i<4;i++){
    int r = lr + i*16;
    float4 v = *(const float4*)(in + (size_t)(r0 + r)*rstride + c0 + lc);
    tile[lc+0][r] = f2bf(v.x);
    tile[lc+1][r] = f2bf(v.y);
    tile[lc+2][r] = f2bf(v.z);
    tile[lc+3][r] = f2bf(v.w);
  }
  __syncthreads();
  int oc  = threadIdx.x >> 2;         // 0..63
  int orr = (threadIdx.x & 3) * 16;   // 0,16,32,48
  uint4 a  = *(const uint4*)&tile[oc][orr];
  uint4 b2 = *(const uint4*)&tile[oc][orr + 8];
  *(uint4*)(out + (size_t)(c0+oc)*R + r0 + orr)     = a;
  *(uint4*)(out + (size_t)(c0+oc)*R + r0 + orr + 8) = b2;
}

// ---- merged qkv weight transpose: x<64 -> q, x<80 -> k, else v --------------------
__global__ void cast_transpose_qkv(const float* __restrict__ qw, const float* __restrict__ kw,
                                   const float* __restrict__ vw, u16* __restrict__ wqkvT)
{
  __shared__ u16 tile[64][72];
  int bx = blockIdx.x;
  const float* in; u16* out; int rstride, c0;
  if(bx < 64){       in = qw; out = wqkvT;                        rstride = 4096; c0 = bx*64; }
  else if(bx < 80){  in = kw; out = wqkvT + (size_t)4096*2048;    rstride = 1024; c0 = (bx-64)*64; }
  else {             in = vw; out = wqkvT + (size_t)5120*2048;    rstride = 1024; c0 = (bx-80)*64; }
  const int R = 2048;
  int r0 = blockIdx.y*64;
  int lr = threadIdx.x >> 4;
  int lc = (threadIdx.x & 15) * 4;
  #pragma unroll
  for(int i=0;i<4;i++){
    int r = lr + i*16;
    float4 v = *(const float4*)(in + (size_t)(r0 + r)*rstride + c0 + lc);
    tile[lc+0][r] = f2bf(v.x);
    tile[lc+1][r] = f2bf(v.y);
    tile[lc+2][r] = f2bf(v.z);
    tile[lc+3][r] = f2bf(v.w);
  }
  __syncthreads();
  int oc  = threadIdx.x >> 2;
  int orr = (threadIdx.x & 3) * 16;
  uint4 a  = *(const uint4*)&tile[oc][orr];
  uint4 b2 = *(const uint4*)&tile[oc][orr + 8];
  *(uint4*)(out + (size_t)(c0+oc)*R + r0 + orr)     = a;
  *(uint4*)(out + (size_t)(c0+oc)*R + r0 + orr + 8) = b2;
}

// ---- tiny transpose: gwT[e][c] = gw[c][e]  (2048x8 -> 8x2048 fp32) ----------------
__global__ void transpose_gate(const float* __restrict__ gw, float* __restrict__ gwT)
{
  int i = blockIdx.x*256 + threadIdx.x;      // 16384 elems
  int c = i >> 3, e = i & 7;
  gwT[(size_t)e*CDIM + c] = gw[(size_t)c*NE + e];
}

// ---------------- transpose bf16->bf16: out[c][r] = in[r][c] -----------------------
__global__ void transpose_u16(const u16* __restrict__ in, u16* __restrict__ out,
                              int R, int Cc, int rstride, int d1,
                              long long s_hi, long long s_lo)
{
  __shared__ u16 tile[32][34];
  int z = blockIdx.z;
  in += (long long)(z / d1) * s_hi + (long long)(z % d1) * s_lo;
  out += (size_t)z * R * Cc;
  int tx = threadIdx.x & 31, ty = threadIdx.x >> 5;   // 32 x 8
  int r0 = blockIdx.y * 32, c0 = blockIdx.x * 32;
  #pragma unroll
  for(int i=0;i<4;i++){
    int r = r0 + ty + i*8;
    if(r < R && c0 + tx < Cc) tile[ty + i*8][tx] = in[(size_t)r * rstride + c0 + tx];
  }
  __syncthreads();
  #pragma unroll
  for(int i=0;i<4;i++){
    int c = c0 + ty + i*8;
    if(c < Cc && r0 + tx < R) out[(size_t)c * R + r0 + tx] = tile[tx][ty + i*8];
  }
}

// ---------------- RMSNorm over C=2048, write bf16 (+ optional fp32) ----------------
__global__ void rmsnorm_kernel(const float* __restrict__ x, const float* __restrict__ w,
                               u16* __restrict__ outb, float* __restrict__ outf)
{
  __shared__ float sbuf[4];
  int row = blockIdx.x;
  const float* xr = x + (size_t)row * CDIM;
  int t0 = threadIdx.x * 8;
  float4 v0 = *(const float4*)(xr + t0);
  float4 v1 = *(const float4*)(xr + t0 + 4);
  float a[8] = {v0.x,v0.y,v0.z,v0.w,v1.x,v1.y,v1.z,v1.w};
  float ss = 0.f;
  #pragma unroll
  for(int i=0;i<8;i++) ss += a[i]*a[i];
  #pragma unroll
  for(int o=32;o>0;o>>=1) ss += __shfl_xor(ss, o);
  if((threadIdx.x & 63) == 0) sbuf[threadIdx.x >> 6] = ss;
  __syncthreads();
  float tot = sbuf[0]+sbuf[1]+sbuf[2]+sbuf[3];
  float r = rsqrtf(tot * (1.0f/CDIM) + 1e-6f);
  float4 w0 = *(const float4*)(w + t0);
  float4 w1 = *(const float4*)(w + t0 + 4);
  float wv[8] = {w0.x,w0.y,w0.z,w0.w,w1.x,w1.y,w1.z,w1.w};
  #pragma unroll
  for(int i=0;i<8;i++){
    float o = a[i] * r * wv[i];
    outb[(size_t)row*CDIM + t0 + i] = f2bf(o);
    if(outf) outf[(size_t)row*CDIM + t0 + i] = o;
  }
}

// ======== qkv pipelined 128x128 GEMM (oproj structure): Cb[bf16] = A @ Bt^T ========
__global__ __launch_bounds__(256) void gemm_qkv_pipe(const u16* __restrict__ A,
                                                     const u16* __restrict__ Bt,
                                                     u16* __restrict__ Cb,
                                                     int M, int N, int K)
{
  extern __shared__ u16 lds[];
  int nwg = gridDim.x;
  int wgid = xcd_swz(blockIdx.x, nwg);
  int nbx = N >> 7;
  int bys = wgid / nbx, bxs = wgid % nbx;
  const int NT = K >> 6;
  int tid = threadIdx.x;
  int lane = tid&63, g = lane>>4, cl = lane&15;
  int w = tid>>6, wr = w>>1, wc = w&1;
  int br = bys*128, bc = bxs*128;
  int rowc[4], slotc[4], srcoff[4];
  #pragma unroll
  for(int l=0;l<4;l++){
    int c = l*256 + tid;
    rowc[l]  = c >> 3;
    slotc[l] = c & 7;
    srcoff[l] = (slotc[l] ^ (rowc[l] & 7)) * 8;
  }
  f32x4 acc[4][4];
  #pragma unroll
  for(int m=0;m<4;m++)
    #pragma unroll
    for(int n=0;n<4;n++) acc[m][n] = (f32x4){0.f,0.f,0.f,0.f};

  auto stage = [&](int t, int b){
    int k0 = t << 6;
    #pragma unroll
    for(int l=0;l<4;l++)
      GLOAD_LDS16(A + (size_t)(br + rowc[l])*K + k0 + srcoff[l],
                  &lds[b*8192 + rowc[l]*64 + slotc[l]*8]);
    #pragma unroll
    for(int l=0;l<4;l++)
      GLOAD_LDS16(Bt + (size_t)(bc + rowc[l])*K + k0 + srcoff[l],
                  &lds[16384 + b*8192 + rowc[l]*64 + slotc[l]*8]);
  };

  stage(0, 0);
  for(int t=0;t<NT;t++){
    int buf = t & 1;
    if(t+1 < NT){
      stage(t+1, buf^1);
      asm volatile("s_waitcnt vmcnt(8)" ::: "memory");
    } else {
      asm volatile("s_waitcnt vmcnt(0)" ::: "memory");
    }
    asm volatile("s_barrier" ::: "memory");
    const u16* As_ = &lds[buf*8192];
    const u16* Bs_ = &lds[16384 + buf*8192];
    __builtin_amdgcn_s_setprio(1);
    #pragma unroll
    for(int kk=0;kk<2;kk++){
      bf16x8 a[4], b[4];
      #pragma unroll
      for(int m=0;m<4;m++){
        int row = wr*64 + m*16 + cl;
        int sl  = ((4*kk + g) ^ (row & 7)) * 8;
        a[m] = *(const bf16x8*)&As_[row*64 + sl];
      }
      #pragma unroll
      for(int n=0;n<4;n++){
        int row = wc*64 + n*16 + cl;
        int sl  = ((4*kk + g) ^ (row & 7)) * 8;
        b[n] = *(const bf16x8*)&Bs_[row*64 + sl];
      }
      #pragma unroll
      for(int m=0;m<4;m++)
        #pragma unroll
        for(int n=0;n<4;n++)
          acc[m][n] = mfma_bf16(a[m], b[n], acc[m][n]);
    }
    __builtin_amdgcn_s_setprio(0);
    asm volatile("s_barrier" ::: "memory");
  }
  #pragma unroll
  for(int m=0;m<4;m++)
    #pragma unroll
    for(int n=0;n<4;n++)
      #pragma unroll
      for(int j=0;j<4;j++){
        int row = br + wr*64 + m*16 + g*4 + j;
        int col = bc + wc*64 + n*16 + cl;
        Cb[(size_t)row*N + col] = f2bf(acc[m][n][j]);
      }
}

// ======== o-proj pipelined 128x128 GEMM: out[fp32] = A @ Bt^T + addsrc ==============
__global__ __launch_bounds__(256) void gemm_oproj_pipe(const u16* __restrict__ A,
                                                       const u16* __restrict__ Bt,
                                                       float* __restrict__ C,
                                                       const float* __restrict__ addsrc,
                                                       int M, int N, int K)
{
  extern __shared__ u16 lds[];
  int nwg = gridDim.x;
  int wgid = xcd_swz(blockIdx.x, nwg);
  int nbx = N >> 7;
  int bys = wgid / nbx, bxs = wgid % nbx;
  const int NT = K >> 6;
  int tid = threadIdx.x;
  int lane = tid&63, g = lane>>4, cl = lane&15;
  int w = tid>>6, wr = w>>1, wc = w&1;
  int br = bys*128, bc = bxs*128;
  int rowc[4], slotc[4], srcoff[4];
  #pragma unroll
  for(int l=0;l<4;l++){
    int c = l*256 + tid;
    rowc[l]  = c >> 3;
    slotc[l] = c & 7;
    srcoff[l] = (slotc[l] ^ (rowc[l] & 7)) * 8;
  }
  f32x4 acc[4][4];
  #pragma unroll
  for(int m=0;m<4;m++)
    #pragma unroll
    for(int n=0;n<4;n++) acc[m][n] = (f32x4){0.f,0.f,0.f,0.f};

  auto stage = [&](int t, int b){
    int k0 = t << 6;
    #pragma unroll
    for(int l=0;l<4;l++)
      GLOAD_LDS16(A + (size_t)(br + rowc[l])*K + k0 + srcoff[l],
                  &lds[b*8192 + rowc[l]*64 + slotc[l]*8]);
    #pragma unroll
    for(int l=0;l<4;l++)
      GLOAD_LDS16(Bt + (size_t)(bc + rowc[l])*K + k0 + srcoff[l],
                  &lds[16384 + b*8192 + rowc[l]*64 + slotc[l]*8]);
  };

  stage(0, 0);
  for(int t=0;t<NT;t++){
    int buf = t & 1;
    if(t+1 < NT){
      stage(t+1, buf^1);
      asm volatile("s_waitcnt vmcnt(8)" ::: "memory");
    } else {
      asm volatile("s_waitcnt vmcnt(0)" ::: "memory");
    }
    asm volatile("s_barrier" ::: "memory");
    const u16* As_ = &lds[buf*8192];
    const u16* Bs_ = &lds[16384 + buf*8192];
    __builtin_amdgcn_s_setprio(1);
    #pragma unroll
    for(int kk=0;kk<2;kk++){
      bf16x8 a[4], b[4];
      #pragma unroll
      for(int m=0;m<4;m++){
        int row = wr*64 + m*16 + cl;
        int sl  = ((4*kk + g) ^ (row & 7)) * 8;
        a[m] = *(const bf16x8*)&As_[row*64 + sl];
      }
      #pragma unroll
      for(int n=0;n<4;n++){
        int row = wc*64 + n*16 + cl;
        int sl  = ((4*kk + g) ^ (row & 7)) * 8;
        b[n] = *(const bf16x8*)&Bs_[row*64 + sl];
      }
      #pragma unroll
      for(int m=0;m<4;m++)
        #pragma unroll
        for(int n=0;n<4;n++)
          acc[m][n] = mfma_bf16(a[m], b[n], acc[m][n]);
    }
    __builtin_amdgcn_s_setprio(0);
    asm volatile("s_barrier" ::: "memory");
  }
  #pragma unroll
  for(int m=0;m<4;m++)
    #pragma unroll
    for(int n=0;n<4;n++)
      #pragma unroll
      for(int j=0;j<4;j++){
        int row = br + wr*64 + m*16 + g*4 + j;
        int col = bc + wc*64 + n*16 + cl;
        C[(size_t)row*N + col] = acc[m][n][j] + addsrc[(size_t)row*N + col];
      }
}

// ------- per-head RMSNorm (D=128) + RoPE; q additionally scaled by 1/sqrt(D) -------
__global__ void qk_norm_rope(const u16* __restrict__ qkv, const float* __restrict__ cosb,
                             const float* __restrict__ sinb, const float* __restrict__ qnw,
                             const float* __restrict__ knw,
                             u16* __restrict__ qb, u16* __restrict__ kb)
{
  __shared__ float red[2];
  __shared__ float buf[128];
  int bt = blockIdx.x;             // b*T + t
  int head = blockIdx.y;           // 0..39 : 32 q heads then 8 kv heads
  int d = threadIdx.x;             // 0..127
  int b = bt >> 10, t = bt & 1023;
  bool isq = head < NH;
  const u16* src = qkv + (size_t)bt*6144 + (isq ? head*DH : 4096 + (head-NH)*DH);
  float v = bf2f(src[d]);
  float ss = v*v;
  #pragma unroll
  for(int o=32;o>0;o>>=1) ss += __shfl_xor(ss, o);
  if((threadIdx.x & 63) == 0) red[threadIdx.x >> 6] = ss;
  __syncthreads();
  float tot = red[0] + red[1];
  float r = rsqrtf(tot * (1.0f/DH) + 1e-6f);
  float nv = v * r * (isq ? qnw[d] : knw[d]);
  buf[d] = nv;
  __syncthreads();
  float rot = (d < 64) ? -buf[d+64] : buf[d-64];
  float cs = cosb[(size_t)bt*DH + d], sn = sinb[(size_t)bt*DH + d];
  float ov = nv*cs + rot*sn;
  if(isq) ov *= 0.08838834764831845f;   // fold 1/sqrt(128) into q
  if(isq) qb[(((size_t)b*NH  + head)     *TSEQ + t)*DH + d] = f2bf(ov);
  else    kb[(((size_t)b*NKV + (head-NH))*TSEQ + t)*DH + d] = f2bf(ov);
}

// ---- flash attention: gload_lds + T2-swizzled K/V, ones-col l, defer-max ----------
__global__ __launch_bounds__(256) void attn_kernel(const u16* __restrict__ qb,
                                                   const u16* __restrict__ kb,
                                                   const u16* __restrict__ vt,
                                                   u16* __restrict__ aob)
{
  __shared__ u16 Ks[64*128];        // linear [64][128], slot^(row&7) swizzled (16B slots)
  __shared__ u16 Vs[144*64];        // linear [144][64]; rows 128..143 static (ones row @128)
  __shared__ u16 Ps[4][32][72];     // per-wave P tile [qrow][kv], pad 8
  int tid = threadIdx.x;
  int w = tid>>6, lane = tid&63, g = lane>>4, cl = lane&15;
  int nwg = gridDim.x * gridDim.y * gridDim.z;
  int orig = (blockIdx.z * gridDim.y + blockIdx.y) * gridDim.x + blockIdx.x;
  int wgid = xcd_swz(orig, nwg);
  int bxs = wgid % gridDim.x;
  int bys = (wgid / gridDim.x) % gridDim.y;
  int bzs = wgid / (gridDim.x * gridDim.y);
  int b = bzs, kvh = bys;
  int qt = (gridDim.x - 1) - bxs;     // big tiles first
  int q0 = qt*32;
  int h = kvh*4 + w;
  const u16* qp = qb + (((size_t)b*NH  + h  )*TSEQ)*DH;
  const u16* kp = kb + (((size_t)b*NKV + kvh)*TSEQ)*DH;
  const u16* vp = vt + (((size_t)b*NKV + kvh)*DH)*TSEQ;
  // static ones/zero rows 128..143 of Vs (row 128 = 1.0, rest 0); row128&7==0 -> identity swz
  for(int idx = tid; idx < 16*64; idx += 256){
    int r = idx >> 6, c2 = idx & 63;
    Vs[(128 + r)*64 + c2] = (r == 0) ? (u16)0x3F80 : (u16)0;
  }
  // per-thread staging geometry (fixed): K row=c>>4 slot=c&15; V row=c>>3 slot=c&7
  int kRow[4], kDst[4], kSrc[4], vRow[4], vDst[4], vSrc[4];
  #pragma unroll
  for(int it=0; it<4; it++){
    int c = tid + it*256;
    kRow[it] = c >> 4;
    int ks = c & 15;
    kDst[it] = kRow[it]*128 + ks*8;
    kSrc[it] = (ks ^ (kRow[it] & 7)) * 8;
    vRow[it] = c >> 3;
    int vs = c & 7;
    vDst[it] = vRow[it]*64 + vs*8;
    vSrc[it] = (vs ^ (vRow[it] & 7)) * 8;
  }
  bf16x8 aq[2][4];
  #pragma unroll
  for(int m=0;m<2;m++)
    #pragma unroll
    for(int kd=0;kd<4;kd++)
      aq[m][kd] = *(const bf16x8*)(qp + (size_t)(q0 + m*16 + cl)*DH + kd*32 + g*8);
  f32x4 accO[2][9];
  #pragma unroll
  for(int m=0;m<2;m++)
    #pragma unroll
    for(int n=0;n<9;n++) accO[m][n] = (f32x4){0.f,0.f,0.f,0.f};
  float mr[2][4];
  #pragma unroll
  for(int m=0;m<2;m++)
    #pragma unroll
    for(int j=0;j<4;j++) mr[m][j] = -1e30f;
  for(int kv0 = 0; kv0 < q0 + 32; kv0 += 64){
    // stage K 64x128 and V^T 128x64 via global_load_lds (linear dest, swizzled source)
    #pragma unroll
    for(int it=0; it<4; it++){
      GLOAD_LDS16(kp + (size_t)(kv0 + kRow[it])*DH + kSrc[it], &Ks[kDst[it]]);
      GLOAD_LDS16(vp + (size_t)vRow[it]*TSEQ + kv0 + vSrc[it], &Vs[vDst[it]]);
    }
    __syncthreads();
    f32x4 sc[2][4];
    #pragma unroll
    for(int m=0;m<2;m++)
      #pragma unroll
      for(int n=0;n<4;n++) sc[m][n] = (f32x4){0.f,0.f,0.f,0.f};
    __builtin_amdgcn_s_setprio(1);
    #pragma unroll
    for(int kd=0;kd<4;kd++){
      bf16x8 bk[4];
      #pragma unroll
      for(int n=0;n<4;n++){
        int row = n*16 + cl;                      // row&7 == cl&7
        bk[n] = *(const bf16x8*)&Ks[row*128 + (((kd*4 + g) ^ (cl & 7))*8)];
      }
      #pragma unroll
      for(int m=0;m<2;m++)
        #pragma unroll
        for(int n=0;n<4;n++)
          sc[m][n] = mfma_bf16(aq[m][kd], bk[n], sc[m][n]);
    }
    __builtin_amdgcn_s_setprio(0);
    // causal mask only on the diagonal tile
    if(kv0 + 63 > q0){
      #pragma unroll
      for(int m=0;m<2;m++)
        #pragma unroll
        for(int n=0;n<4;n++)
          #pragma unroll
          for(int j=0;j<4;j++){
            int row = q0 + m*16 + g*4 + j;
            int col = kv0 + n*16 + cl;
            if(col > row) sc[m][n][j] = -1e30f;
          }
    }
    // row max over this tile
    float tmax[2][4];
    #pragma unroll
    for(int m=0;m<2;m++)
      #pragma unroll
      for(int j=0;j<4;j++)
        tmax[m][j] = fmaxf(fmaxf(sc[m][0][j], sc[m][1][j]), fmaxf(sc[m][2][j], sc[m][3][j]));
    #pragma unroll
    for(int o=1;o<16;o<<=1)
      #pragma unroll
      for(int m=0;m<2;m++)
        #pragma unroll
        for(int j=0;j<4;j++) tmax[m][j] = fmaxf(tmax[m][j], __shfl_xor(tmax[m][j], o));
    // wave-uniform defer-max decision (THR=8)
    float grow = -1e30f;
    #pragma unroll
    for(int m=0;m<2;m++)
      #pragma unroll
      for(int j=0;j<4;j++) grow = fmaxf(grow, tmax[m][j] - mr[m][j]);
    grow = fmaxf(grow, __shfl_xor(grow, 16));
    grow = fmaxf(grow, __shfl_xor(grow, 32));
    if(grow > 8.0f){
      #pragma unroll
      for(int m=0;m<2;m++)
        #pragma unroll
        for(int j=0;j<4;j++){
          float mn = fmaxf(mr[m][j], tmax[m][j]);
          float f  = __expf(mr[m][j] - mn);
          mr[m][j] = mn;
          #pragma unroll
          for(int n=0;n<9;n++) accO[m][n][j] *= f;
        }
    }
    // exp
    #pragma unroll
    for(int m=0;m<2;m++)
      #pragma unroll
      for(int n=0;n<4;n++)
        #pragma unroll
        for(int j=0;j<4;j++)
          sc[m][n][j] = __expf(sc[m][n][j] - mr[m][j]);
    // write P to per-wave LDS
    #pragma unroll
    for(int m=0;m<2;m++)
      #pragma unroll
      for(int n=0;n<4;n++)
        #pragma unroll
        for(int j=0;j<4;j++)
          Ps[w][m*16 + g*4 + j][n*16 + cl] = f2bf(sc[m][n][j]);
    bf16x8 pa[2][2];
    #pragma unroll
    for(int m=0;m<2;m++)
      #pragma unroll
      for(int s2=0;s2<2;s2++)
        pa[m][s2] = *(const bf16x8*)&Ps[w][m*16 + cl][s2*32 + g*8];
    // PV (+ ones-column tile n=8 accumulating row-sum l); V rows swizzled by cl&7
    __builtin_amdgcn_s_setprio(1);
    #pragma unroll
    for(int n=0;n<9;n++){
      #pragma unroll
      for(int s2=0;s2<2;s2++){
        bf16x8 bv = *(const bf16x8*)&Vs[(n*16 + cl)*64 + (((s2*4 + g) ^ (cl & 7))*8)];
        #pragma unroll
        for(int m=0;m<2;m++)
          accO[m][n] = mfma_bf16(pa[m][s2], bv, accO[m][n]);
      }
    }
    __builtin_amdgcn_s_setprio(0);
    __syncthreads();
  }
  // epilogue: l lives in accO[m][8], col 0 (lane cl=0 of each g-group)
  #pragma unroll
  for(int m=0;m<2;m++){
    float linv[4];
    #pragma unroll
    for(int j=0;j<4;j++){
      float l = __shfl(accO[m][8][j], lane & 48);
      linv[j] = 1.0f / l;
    }
    #pragma unroll
    for(int n=0;n<8;n++)
      #pragma unroll
      for(int j=0;j<4;j++){
        int row = q0 + m*16 + g*4 + j;
        float v = accO[m][n][j] * linv[j];
        aob[((size_t)b*TSEQ + row)*(NH*DH) + h*DH + n*16 + cl] = f2bf(v);
      }
  }
}

// ---------------- routing: fp32 h2f + coalesced gwT, softmax, top-2, bucket --------
__global__ void route_kernel(const float* __restrict__ h2f, const float* __restrict__ gwT,
                             int* __restrict__ cnt, int* __restrict__ bidx,
                             float* __restrict__ bw)
{
  int lane = threadIdx.x & 63;
  int token = blockIdx.x*4 + (threadIdx.x >> 6);
  float acc[8];
  #pragma unroll
  for(int e=0;e<8;e++) acc[e]=0.f;
  for(int c0 = lane*4; c0 < CDIM; c0 += 256){
    float4 hv = *(const float4*)(h2f + (size_t)token*CDIM + c0);
    #pragma unroll
    for(int e=0;e<8;e++){
      float4 gv = *(const float4*)(gwT + (size_t)e*CDIM + c0);
      acc[e] += hv.x*gv.x + hv.y*gv.y + hv.z*gv.z + hv.w*gv.w;
    }
  }
  #pragma unroll
  for(int o=32;o>0;o>>=1)
    #pragma unroll
    for(int e=0;e<8;e++) acc[e] += __shfl_xor(acc[e], o);
  if(lane==0){
    float mx = acc[0];
    #pragma unroll
    for(int e=1;e<8;e++) mx = fmaxf(mx, acc[e]);
    float rw[8]; float s=0.f;
    #pragma unroll
    for(int e=0;e<8;e++){ rw[e] = __expf(acc[e]-mx); s += rw[e]; }
    #pragma unroll
    for(int e=0;e<8;e++) rw[e] /= s;
    int i0=0;
    #pragma unroll
    for(int e=1;e<8;e++) if(rw[e] > rw[i0]) i0=e;
    int i1 = (i0==0)?1:0;
    #pragma unroll
    for(int e=0;e<8;e++) if(e!=i0 && rw[e] > rw[i1]) i1=e;
    float tw0=rw[i0], tw1=rw[i1];
    float s1 = tw0+tw1+1e-9f;
    float a0 = tw0/s1, a1 = tw1/s1;
    float s2 = a0+a1+1e-9f;
    float w0 = a0/s2, w1 = a1/s2;
    int sl0 = atomicAdd(&cnt[i0],1);
    bidx[i0*CAP + sl0] = token; bw[i0*CAP + sl0] = w0;
    int sl1 = atomicAdd(&cnt[i1],1);
    bidx[i1*CAP + sl1] = token; bw[i1*CAP + sl1] = w1;
  }
}

// ==== MoE gate_up pipelined 128x(64G+64U) GEMM, expert->XCD pinned, 64KB LDS =======
// grid 1536: e=d&7, j=d>>3: y=j/12 (row tile of 128 slots), x=j%12 (64-col tile).
// LDS elems: A[2][8192] @0, Bg[2][4096] @16384, Bu[2][4096] @24576. Total 64KB -> 2 blk/CU.
__global__ __launch_bounds__(256) void gemm_gateup_pipe(const u16* __restrict__ h2b,
                                                        const u16* __restrict__ gupT,
                                                        u16* __restrict__ act,
                                                        const int* __restrict__ bidx,
                                                        const int* __restrict__ cnt)
{
  extern __shared__ u16 lds[];
  int d = blockIdx.x;
  int e = d & 7, j = d >> 3;
  int y = j / 12, x = j % 12;
  int nc = cnt[e];
  int sr = y*128;
  if(sr >= nc) return;
  const int K = CDIM, NT = K >> 6;
  const u16* Btg = gupT + (size_t)e*1536*CDIM + (size_t)(x*64)*CDIM;
  const u16* Btu = Btg + (size_t)768*CDIM;
  const int* be = bidx + e*CAP;
  int tid = threadIdx.x;
  int lane = tid&63, g = lane>>4, cl = lane&15;
  int w = tid>>6, wr = w>>1, wc = w&1;
  // A staging: 4 chunks/thread (128 rows x 8 slots); B staging: 2 chunks/thread (64 rows x 8 slots)
  int rowA[4], slotA[4], srcA[4];
  long long atok[4];
  #pragma unroll
  for(int l=0;l<4;l++){
    int c = l*256 + tid;
    rowA[l]  = c >> 3;
    slotA[l] = c & 7;
    srcA[l] = (slotA[l] ^ (rowA[l] & 7)) * 8;
    int t = be[sr + rowA[l]];
    if(t < 0 || t >= NTOK) t = 0;
    atok[l] = (long long)t * CDIM;
  }
  int rowB[2], slotB[2], srcB[2];
  #pragma unroll
  for(int l=0;l<2;l++){
    int c = l*256 + tid;
    rowB[l]  = c >> 3;
    slotB[l] = c & 7;
    srcB[l] = (slotB[l] ^ (rowB[l] & 7)) * 8;
  }
  f32x4 accG[4][2], accU[4][2];
  #pragma unroll
  for(int m=0;m<4;m++)
    #pragma unroll
    for(int n=0;n<2;n++){ accG[m][n] = (f32x4){0.f,0.f,0.f,0.f}; accU[m][n] = (f32x4){0.f,0.f,0.f,0.f}; }

  auto stage = [&](int t, int b){
    int k0 = t << 6;
    #pragma unroll
    for(int l=0;l<4;l++)
      GLOAD_LDS16(h2b + atok[l] + k0 + srcA[l],
                  &lds[b*8192 + rowA[l]*64 + slotA[l]*8]);
    #pragma unroll
    for(int l=0;l<2;l++)
      GLOAD_LDS16(Btg + (size_t)rowB[l]*K + k0 + srcB[l],
                  &lds[16384 + b*4096 + rowB[l]*64 + slotB[l]*8]);
    #pragma unroll
    for(int l=0;l<2;l++)
      GLOAD_LDS16(Btu + (size_t)rowB[l]*K + k0 + srcB[l],
                  &lds[24576 + b*4096 + rowB[l]*64 + slotB[l]*8]);
  };

  stage(0, 0);
  for(int t=0;t<NT;t++){
    int buf = t & 1;
    if(t+1 < NT){
      stage(t+1, buf^1);
      asm volatile("s_waitcnt vmcnt(8)" ::: "memory");
    } else {
      asm volatile("s_waitcnt vmcnt(0)" ::: "memory");
    }
    asm volatile("s_barrier" ::: "memory");
    const u16* As_ = &lds[buf*8192];
    const u16* Bg_ = &lds[16384 + buf*4096];
    const u16* Bu_ = &lds[24576 + buf*4096];
    __builtin_amdgcn_s_setprio(1);
    #pragma unroll
    for(int kk=0;kk<2;kk++){
      bf16x8 a[4], bg[2], bu[2];
      #pragma unroll
      for(int m=0;m<4;m++){
        int row = wr*64 + m*16 + cl;
        int sl  = ((4*kk + g) ^ (row & 7)) * 8;
        a[m] = *(const bf16x8*)&As_[row*64 + sl];
      }
      #pragma unroll
      for(int n=0;n<2;n++){
        int row = wc*32 + n*16 + cl;
        int sl  = ((4*kk + g) ^ (row & 7)) * 8;
        bg[n] = *(const bf16x8*)&Bg_[row*64 + sl];
        bu[n] = *(const bf16x8*)&Bu_[row*64 + sl];
      }
      #pragma unroll
      for(int m=0;m<4;m++)
        #pragma unroll
        for(int n=0;n<2;n++){
          accG[m][n] = mfma_bf16(a[m], bg[n], accG[m][n]);
          accU[m][n] = mfma_bf16(a[m], bu[n], accU[m][n]);
        }
    }
    __builtin_amdgcn_s_setprio(0);
    asm volatile("s_barrier" ::: "memory");
  }
  #pragma unroll
  for(int m=0;m<4;m++)
    #pragma unroll
    for(int n=0;n<2;n++)
      #pragma unroll
      for(int jj=0;jj<4;jj++){
        int slot = sr + wr*64 + m*16 + g*4 + jj;
        int col  = x*64 + wc*32 + n*16 + cl;
        float gv = accG[m][n][jj], uv = accU[m][n][jj];
        float av = gv / (1.f + __expf(-gv)) * uv;
        act[((size_t)e*CAP + slot)*FDIM + col] = f2bf(av);
      }
}

// ==== MoE down pipelined 128x128 GEMM, expert->XCD pinned, scatter-atomic ==========
__global__ __launch_bounds__(256) void gemm_down_pipe(const u16* __restrict__ act,
                                                      const u16* __restrict__ downT,
                                                      float* __restrict__ out,
                                                      const int* __restrict__ bidx,
                                                      const float* __restrict__ bw,
                                                      const int* __restrict__ cnt)
{
  extern __shared__ u16 lds[];
  int d = blockIdx.x;
  int e = d & 7, j = d >> 3;
  int y = j >> 4, x = j & 15;
  int nc = cnt[e];
  int sr = y*128;
  if(sr >= nc) return;
  const int K = FDIM, NT = K >> 6;   // 12 steps
  const u16* A  = act   + ((size_t)e*CAP + sr)*FDIM;
  const u16* Bt = downT + (size_t)e*CDIM*FDIM + (size_t)(x*128)*FDIM;
  const int* be = bidx + e*CAP;
  const float* bwe = bw + e*CAP;
  int tid = threadIdx.x;
  int lane = tid&63, g = lane>>4, cl = lane&15;
  int w = tid>>6, wr = w>>1, wc = w&1;
  int rowc[4], slotc[4], srcoff[4];
  #pragma unroll
  for(int l=0;l<4;l++){
    int c = l*256 + tid;
    rowc[l]  = c >> 3;
    slotc[l] = c & 7;
    srcoff[l] = (slotc[l] ^ (rowc[l] & 7)) * 8;
  }
  f32x4 acc[4][4];
  #pragma unroll
  for(int m=0;m<4;m++)
    #pragma unroll
    for(int n=0;n<4;n++) acc[m][n] = (f32x4){0.f,0.f,0.f,0.f};

  auto stage = [&](int t, int b){
    int k0 = t << 6;
    #pragma unroll
    for(int l=0;l<4;l++)
      GLOAD_LDS16(A + (size_t)rowc[l]*K + k0 + srcoff[l],
                  &lds[b*8192 + rowc[l]*64 + slotc[l]*8]);
    #pragma unroll
    for(int l=0;l<4;l++)
      GLOAD_LDS16(Bt + (size_t)rowc[l]*K + k0 + srcoff[l],
                  &lds[16384 + b*8192 + rowc[l]*64 + slotc[l]*8]);
  };

  stage(0, 0);
  for(int t=0;t<NT;t++){
    int buf = t & 1;
    if(t+1 < NT){
      stage(t+1, buf^1);
      asm volatile("s_waitcnt vmcnt(8)" ::: "memory");
    } else {
      asm volatile("s_waitcnt vmcnt(0)" ::: "memory");
    }
    asm volatile("s_barrier" ::: "memory");
    const u16* As_ = &lds[buf*8192];
    const u16* Bs_ = &lds[16384 + buf*8192];
    __builtin_amdgcn_s_setprio(1);
    #pragma unroll
    for(int kk=0;kk<2;kk++){
      bf16x8 a[4], b[4];
      #pragma unroll
      for(int m=0;m<4;m++){
        int row = wr*64 + m*16 + cl;
        int sl  = ((4*kk + g) ^ (row & 7)) * 8;
        a[m] = *(const bf16x8*)&As_[row*64 + sl];
      }
      #pragma unroll
      for(int n=0;n<4;n++){
        int row = wc*64 + n*16 + cl;
        int sl  = ((4*kk + g) ^ (row & 7)) * 8;
        b[n] = *(const bf16x8*)&Bs_[row*64 + sl];
      }
      #pragma unroll
      for(int m=0;m<4;m++)
        #pragma unroll
        for(int n=0;n<4;n++)
          acc[m][n] = mfma_bf16(a[m], b[n], acc[m][n]);
    }
    __builtin_amdgcn_s_setprio(0);
    asm volatile("s_barrier" ::: "memory");
  }
  #pragma unroll
  for(int m=0;m<4;m++)
    #pragma unroll
    for(int jj=0;jj<4;jj++){
      int slot = sr + wr*64 + m*16 + g*4 + jj;
      if(slot < nc){
        int tok = be[slot];
        float wgt = bwe[slot];
        #pragma unroll
        for(int n=0;n<4;n++){
          int col = x*128 + wc*64 + n*16 + cl;
          atomicAdd(out + (size_t)tok*CDIM + col, wgt * acc[m][n][jj]);
        }
      }
    }
}

// ------------------------------------ launch ---------------------------------------
extern "C" void kernel_launch(void* const* d_in, const int* in_sizes, int n_in,
                              void* d_out, int out_size, void* d_ws, size_t ws_size,
                              hipStream_t stream)
{
  const float* x     = (const float*)d_in[0];
  const float* cosb  = (const float*)d_in[1];
  const float* sinb  = (const float*)d_in[2];
  const float* ln1w  = (const float*)d_in[3];
  const float* qw    = (const float*)d_in[4];
  const float* kw    = (const float*)d_in[5];
  const float* vw    = (const float*)d_in[6];
  const float* ow    = (const float*)d_in[7];
  const float* qnw   = (const float*)d_in[8];
  const float* knw   = (const float*)d_in[9];
  const float* ln2w  = (const float*)d_in[10];
  const float* gatew = (const float*)d_in[11];
  const float* gupw  = (const float*)d_in[12];
  const float* downw = (const float*)d_in[13];
  float* out = (float*)d_out;

  char* ws = (char*)d_ws;
  size_t off = 0;
  auto alloc = [&](size_t bytes)->char*{
    char* p = ws + off;
    off = (off + bytes + 255) & ~(size_t)255;
    return p;
  };
  u16*   wqkvT = (u16*)  alloc((size_t)6144*2048*2);
  u16*   owT   = (u16*)  alloc((size_t)2048*4096*2);
  u16*   gupT  = (u16*)  alloc((size_t)8*1536*2048*2);
  u16*   downT = (u16*)  alloc((size_t)8*2048*768*2);
  u16*   h1b   = (u16*)  alloc((size_t)2048*2048*2);
  u16*   qkvb  = (u16*)  alloc((size_t)2048*6144*2);
  u16*   qb    = (u16*)  alloc((size_t)2*32*1024*128*2);
  u16*   kb    = (u16*)  alloc((size_t)2*8*1024*128*2);
  u16*   vt    = (u16*)  alloc((size_t)2*8*1024*128*2);
  u16*   aob   = (u16*)  alloc((size_t)2048*4096*2);
  float* h2f   = (float*)alloc((size_t)2048*2048*4);
  u16*   h2b   = (u16*)  alloc((size_t)2048*2048*2);
  u16*   actb  = (u16*)  alloc((size_t)8*2048*768*2);
  int*   bidx  = (int*)  alloc((size_t)8*2048*4);
  float* bwgt  = (float*)alloc((size_t)8*2048*4);
  float* gwT   = (float*)alloc((size_t)8*2048*4);
  int*   cnt   = (int*)  alloc(64);
  (void)ws_size; (void)in_sizes; (void)n_in; (void)out_size;

  hipMemsetAsync(cnt, 0, 8*sizeof(int), stream);

  // weight transposes/casts (64x64-tile, 16B r/w); q+k+v merged
  cast_transpose_qkv<<<dim3(96,32), 256, 0, stream>>>(qw, kw, vw, wqkvT);
  cast_transpose<<<dim3(32,64,1), 256, 0, stream>>>(ow, owT,      4096, 2048, 2048, 1, 0, 0);
  cast_transpose<<<dim3(24,32,8), 256, 0, stream>>>(gupw, gupT,   2048, 1536, 1536, 8, 0, (long long)2048*1536);
  cast_transpose<<<dim3(32,12,8), 256, 0, stream>>>(downw, downT, 768,  2048, 2048, 8, 0, (long long)768*2048);
  transpose_gate<<<64, 256, 0, stream>>>(gatew, gwT);

  // ln1 + cast
  rmsnorm_kernel<<<2048, 256, 0, stream>>>(x, ln1w, h1b, nullptr);
  // qkv = h @ [q|k|v]  (M=2048, N=6144, K=2048) -> bf16 ; 128x128 pipe, 768 blocks 2/CU
  gemm_qkv_pipe<<<768, 256, 65536, stream>>>(h1b, wqkvT, qkvb, 2048, 6144, 2048);
  // q/k: per-head rmsnorm + rope (+ q*scale) -> bf16
  qk_norm_rope<<<dim3(2048,40), 128, 0, stream>>>(qkvb, cosb, sinb, qnw, knw, qb, kb);
  // v -> (b,kv,D,T) bf16
  transpose_u16<<<dim3(4,32,16), 256, 0, stream>>>(qkvb + 5120, vt, 1024, 128, 6144, 8,
                                                   (long long)1024*6144, 128);
  // attention
  attn_kernel<<<dim3(32,8,2), 256, 0, stream>>>(qb, kb, vt, aob);
  // o-proj + residual -> out  (pipelined 128x128)
  gemm_oproj_pipe<<<256, 256, 65536, stream>>>(aob, owT, out, x, 2048, 2048, 4096);
  // ln2 (fp32 for router + bf16 for experts)
  rmsnorm_kernel<<<2048, 256, 0, stream>>>(out, ln2w, h2b, h2f);
  // routing (fp32 h2f + coalesced gwT)
  route_kernel<<<512, 256, 0, stream>>>(h2f, gwT, cnt, bidx, bwgt);
  // experts: pipelined, expert->XCD pinned; gate_up 128x(64G+64U), 64KB LDS, 2 blk/CU
  gemm_gateup_pipe<<<1536, 256, 65536, stream>>>(h2b, gupT, actb, bidx, cnt);
  gemm_down_pipe<<<2048, 256, 65536, stream>>>(actb, downT, out, bidx, bwgt, cnt);
}

// Round 25
// 443.044 us; speedup vs baseline: 1.0201x; 1.0201x over previous
//
#include <hip/hip_runtime.h>
#include <hip/hip_bf16.h>

typedef short bf16x8 __attribute__((ext_vector_type(8)));
typedef float f32x4 __attribute__((ext_vector_type(4)));
typedef unsigned short u16;

#define NTOK 2048
#define CDIM 2048
#define TSEQ 1024
#define NH   32
#define NKV  8
#define DH   128
#define NE   8
#define FDIM 768
#define CAP  2048

#define GLOAD_LDS16(g, l) \
  __builtin_amdgcn_global_load_lds((const __attribute__((address_space(1))) void*)(g), \
                                   (__attribute__((address_space(3))) void*)(l), 16, 0, 0)

__device__ __forceinline__ u16 f2bf(float f){
  union { float f; unsigned u; } v; v.f = f;
  unsigned r = v.u + 0x7FFFu + ((v.u >> 16) & 1u);
  return (u16)(r >> 16);
}
__device__ __forceinline__ float bf2f(u16 x){
  union { unsigned u; float f; } v; v.u = ((unsigned)x) << 16; return v.f;
}

__device__ __forceinline__ f32x4 mfma_bf16(bf16x8 a, bf16x8 b, f32x4 c){
  return __builtin_amdgcn_mfma_f32_16x16x32_bf16(a, b, c, 0, 0, 0);
}

// bijective XCD-chunk swizzle (m204): orig linear id -> chunked id
__device__ __forceinline__ int xcd_swz(int orig, int nwg){
  int xcd = orig & 7;
  int q = nwg >> 3, r = nwg & 7;
  int base = (xcd < r) ? xcd*(q+1) : r*(q+1) + (xcd-r)*q;
  return base + (orig >> 3);
}

// ---- fast transpose + fp32->bf16 cast, 64x64 tile: out[c][r] = in[r][c] -----------
__global__ void cast_transpose(const float* __restrict__ in, u16* __restrict__ out,
                               int R, int Cc, int rstride, int d1,
                               long long s_hi, long long s_lo)
{
  __shared__ u16 tile[64][72];
  int z = blockIdx.z;
  in  += (long long)(z / d1) * s_hi + (long long)(z % d1) * s_lo;
  out += (size_t)z * R * Cc;
  int r0 = blockIdx.y*64, c0 = blockIdx.x*64;
  int lr = threadIdx.x >> 4;          // 0..15
  int lc = (threadIdx.x & 15) * 4;    // 0..60
  #pragma unroll
  for(int i=0;i<4;i++){
    int r = lr + i*16;
    float4 v = *(const float4*)(in + (size_t)(r0 + r)*rstride + c0 + lc);
    tile[lc+0][r] = f2bf(v.x);
    tile[lc+1][r] = f2bf(v.y);
    tile[lc+2][r] = f2bf(v.z);
    tile[lc+3][r] = f2bf(v.w);
  }
  __syncthreads();
  int oc  = threadIdx.x >> 2;         // 0..63
  int orr = (threadIdx.x & 3) * 16;   // 0,16,32,48
  uint4 a  = *(const uint4*)&tile[oc][orr];
  uint4 b2 = *(const uint4*)&tile[oc][orr + 8];
  *(uint4*)(out + (size_t)(c0+oc)*R + r0 + orr)     = a;
  *(uint4*)(out + (size_t)(c0+oc)*R + r0 + orr + 8) = b2;
}

// ---- merged qkv weight transpose: x<64 -> q, x<80 -> k, else v --------------------
__global__ void cast_transpose_qkv(const float* __restrict__ qw, const float* __restrict__ kw,
                                   const float* __restrict__ vw, u16* __restrict__ wqkvT)
{
  __shared__ u16 tile[64][72];
  int bx = blockIdx.x;
  const float* in; u16* out; int rstride, c0;
  if(bx < 64){       in = qw; out = wqkvT;                        rstride = 4096; c0 = bx*64; }
  else if(bx < 80){  in = kw; out = wqkvT + (size_t)4096*2048;    rstride = 1024; c0 = (bx-64)*64; }
  else {             in = vw; out = wqkvT + (size_t)5120*2048;    rstride = 1024; c0 = (bx-80)*64; }
  const int R = 2048;
  int r0 = blockIdx.y*64;
  int lr = threadIdx.x >> 4;
  int lc = (threadIdx.x & 15) * 4;
  #pragma unroll
  for(int i=0;i<4;i++){
    int r = lr + i*16;
    float4 v = *(const float4*)(in + (size_t)(r0 + r)*rstride + c0 + lc);
    tile[lc+0][r] = f2bf(v.x);
    tile[lc+1][r] = f2bf(v.y);
    tile[lc+2][r] = f2bf(v.z);
    tile[lc+3][r] = f2bf(v.w);
  }
  __syncthreads();
  int oc  = threadIdx.x >> 2;
  int orr = (threadIdx.x & 3) * 16;
  uint4 a  = *(const uint4*)&tile[oc][orr];
  uint4 b2 = *(const uint4*)&tile[oc][orr + 8];
  *(uint4*)(out + (size_t)(c0+oc)*R + r0 + orr)     = a;
  *(uint4*)(out + (size_t)(c0+oc)*R + r0 + orr + 8) = b2;
}

// ---- tiny transpose: gwT[e][c] = gw[c][e]  (2048x8 -> 8x2048 fp32) ----------------
__global__ void transpose_gate(const float* __restrict__ gw, float* __restrict__ gwT)
{
  int i = blockIdx.x*256 + threadIdx.x;      // 16384 elems
  int c = i >> 3, e = i & 7;
  gwT[(size_t)e*CDIM + c] = gw[(size_t)c*NE + e];
}

// ---------------- transpose bf16->bf16: out[c][r] = in[r][c] -----------------------
__global__ void transpose_u16(const u16* __restrict__ in, u16* __restrict__ out,
                              int R, int Cc, int rstride, int d1,
                              long long s_hi, long long s_lo)
{
  __shared__ u16 tile[32][34];
  int z = blockIdx.z;
  in += (long long)(z / d1) * s_hi + (long long)(z % d1) * s_lo;
  out += (size_t)z * R * Cc;
  int tx = threadIdx.x & 31, ty = threadIdx.x >> 5;   // 32 x 8
  int r0 = blockIdx.y * 32, c0 = blockIdx.x * 32;
  #pragma unroll
  for(int i=0;i<4;i++){
    int r = r0 + ty + i*8;
    if(r < R && c0 + tx < Cc) tile[ty + i*8][tx] = in[(size_t)r * rstride + c0 + tx];
  }
  __syncthreads();
  #pragma unroll
  for(int i=0;i<4;i++){
    int c = c0 + ty + i*8;
    if(c < Cc && r0 + tx < R) out[(size_t)c * R + r0 + tx] = tile[tx][ty + i*8];
  }
}

// ---------------- RMSNorm over C=2048, write bf16 (+ optional fp32) ----------------
__global__ void rmsnorm_kernel(const float* __restrict__ x, const float* __restrict__ w,
                               u16* __restrict__ outb, float* __restrict__ outf)
{
  __shared__ float sbuf[4];
  int row = blockIdx.x;
  const float* xr = x + (size_t)row * CDIM;
  int t0 = threadIdx.x * 8;
  float4 v0 = *(const float4*)(xr + t0);
  float4 v1 = *(const float4*)(xr + t0 + 4);
  float a[8] = {v0.x,v0.y,v0.z,v0.w,v1.x,v1.y,v1.z,v1.w};
  float ss = 0.f;
  #pragma unroll
  for(int i=0;i<8;i++) ss += a[i]*a[i];
  #pragma unroll
  for(int o=32;o>0;o>>=1) ss += __shfl_xor(ss, o);
  if((threadIdx.x & 63) == 0) sbuf[threadIdx.x >> 6] = ss;
  __syncthreads();
  float tot = sbuf[0]+sbuf[1]+sbuf[2]+sbuf[3];
  float r = rsqrtf(tot * (1.0f/CDIM) + 1e-6f);
  float4 w0 = *(const float4*)(w + t0);
  float4 w1 = *(const float4*)(w + t0 + 4);
  float wv[8] = {w0.x,w0.y,w0.z,w0.w,w1.x,w1.y,w1.z,w1.w};
  #pragma unroll
  for(int i=0;i<8;i++){
    float o = a[i] * r * wv[i];
    outb[(size_t)row*CDIM + t0 + i] = f2bf(o);
    if(outf) outf[(size_t)row*CDIM + t0 + i] = o;
  }
}

// ======== deep-pipelined 256x192 GEMM (T2+T3+T4+T5): Cb[bf16] = A @ Bt^T ===========
__global__ __launch_bounds__(512, 1) void gemm256(const u16* __restrict__ A,
                                                  const u16* __restrict__ Bt,
                                                  u16* __restrict__ Cb,
                                                  int M, int N, int K)
{
  extern __shared__ u16 lds[];
  const int NT = K >> 6;
  int tid = threadIdx.x;
  int lane = tid & 63, g = lane >> 4, cl = lane & 15;
  int wid = tid >> 6, wr = wid >> 2, wc = wid & 3;
  int br = blockIdx.y * 256, bc = blockIdx.x * 192;
  int rowl[4], slotl[4], srcoff[4];
  #pragma unroll
  for(int l=0;l<4;l++){
    int c = l*512 + tid;
    rowl[l]  = c >> 3;
    slotl[l] = c & 7;
    srcoff[l] = (slotl[l] ^ (rowl[l] & 7)) * 8;   // pre-swizzled global col (elems)
  }
  f32x4 acc[8][3];
  #pragma unroll
  for(int m=0;m<8;m++)
    #pragma unroll
    for(int n=0;n<3;n++) acc[m][n] = (f32x4){0.f,0.f,0.f,0.f};

  auto stage = [&](int t, int b){
    int k0 = t << 6;
    #pragma unroll
    for(int l=0;l<4;l++)
      GLOAD_LDS16(A  + (size_t)(br + rowl[l])*K + k0 + srcoff[l],
                  &lds[b*16384 + rowl[l]*64 + slotl[l]*8]);
    #pragma unroll
    for(int l=0;l<3;l++)
      GLOAD_LDS16(Bt + (size_t)(bc + rowl[l])*K + k0 + srcoff[l],
                  &lds[32768 + b*12288 + rowl[l]*64 + slotl[l]*8]);
  };

  stage(0, 0);
  for(int t=0;t<NT;t++){
    int buf = t & 1;
    if(t+1 < NT){
      stage(t+1, buf^1);
      asm volatile("s_waitcnt vmcnt(7)" ::: "memory");
    } else {
      asm volatile("s_waitcnt vmcnt(0)" ::: "memory");
    }
    asm volatile("s_barrier" ::: "memory");
    const u16* As_ = &lds[buf*16384];
    const u16* Bs_ = &lds[32768 + buf*12288];
    __builtin_amdgcn_s_setprio(1);
    #pragma unroll
    for(int kk=0;kk<2;kk++){
      bf16x8 a[8], b[3];
      #pragma unroll
      for(int m=0;m<8;m++){
        int row = wr*128 + m*16 + cl;
        int sl  = ((4*kk + g) ^ (row & 7)) * 8;
        a[m] = *(const bf16x8*)&As_[row*64 + sl];
      }
      #pragma unroll
      for(int n=0;n<3;n++){
        int row = wc*48 + n*16 + cl;
        int sl  = ((4*kk + g) ^ (row & 7)) * 8;
        b[n] = *(const bf16x8*)&Bs_[row*64 + sl];
      }
      #pragma unroll
      for(int m=0;m<8;m++)
        #pragma unroll
        for(int n=0;n<3;n++)
          acc[m][n] = mfma_bf16(a[m], b[n], acc[m][n]);
    }
    __builtin_amdgcn_s_setprio(0);
    asm volatile("s_barrier" ::: "memory");
  }
  #pragma unroll
  for(int m=0;m<8;m++)
    #pragma unroll
    for(int n=0;n<3;n++)
      #pragma unroll
      for(int j=0;j<4;j++){
        int row = br + wr*128 + m*16 + g*4 + j;
        int col = bc + wc*48 + n*16 + cl;
        Cb[(size_t)row*N + col] = f2bf(acc[m][n][j]);
      }
}

// ======== o-proj pipelined 128x128 GEMM: out[fp32] = A @ Bt^T + addsrc ==============
__global__ __launch_bounds__(256) void gemm_oproj_pipe(const u16* __restrict__ A,
                                                       const u16* __restrict__ Bt,
                                                       float* __restrict__ C,
                                                       const float* __restrict__ addsrc,
                                                       int M, int N, int K)
{
  extern __shared__ u16 lds[];
  int nwg = gridDim.x;
  int wgid = xcd_swz(blockIdx.x, nwg);
  int nbx = N >> 7;
  int bys = wgid / nbx, bxs = wgid % nbx;
  const int NT = K >> 6;
  int tid = threadIdx.x;
  int lane = tid&63, g = lane>>4, cl = lane&15;
  int w = tid>>6, wr = w>>1, wc = w&1;
  int br = bys*128, bc = bxs*128;
  int rowc[4], slotc[4], srcoff[4];
  #pragma unroll
  for(int l=0;l<4;l++){
    int c = l*256 + tid;
    rowc[l]  = c >> 3;
    slotc[l] = c & 7;
    srcoff[l] = (slotc[l] ^ (rowc[l] & 7)) * 8;
  }
  f32x4 acc[4][4];
  #pragma unroll
  for(int m=0;m<4;m++)
    #pragma unroll
    for(int n=0;n<4;n++) acc[m][n] = (f32x4){0.f,0.f,0.f,0.f};

  auto stage = [&](int t, int b){
    int k0 = t << 6;
    #pragma unroll
    for(int l=0;l<4;l++)
      GLOAD_LDS16(A + (size_t)(br + rowc[l])*K + k0 + srcoff[l],
                  &lds[b*8192 + rowc[l]*64 + slotc[l]*8]);
    #pragma unroll
    for(int l=0;l<4;l++)
      GLOAD_LDS16(Bt + (size_t)(bc + rowc[l])*K + k0 + srcoff[l],
                  &lds[16384 + b*8192 + rowc[l]*64 + slotc[l]*8]);
  };

  stage(0, 0);
  for(int t=0;t<NT;t++){
    int buf = t & 1;
    if(t+1 < NT){
      stage(t+1, buf^1);
      asm volatile("s_waitcnt vmcnt(8)" ::: "memory");
    } else {
      asm volatile("s_waitcnt vmcnt(0)" ::: "memory");
    }
    asm volatile("s_barrier" ::: "memory");
    const u16* As_ = &lds[buf*8192];
    const u16* Bs_ = &lds[16384 + buf*8192];
    __builtin_amdgcn_s_setprio(1);
    #pragma unroll
    for(int kk=0;kk<2;kk++){
      bf16x8 a[4], b[4];
      #pragma unroll
      for(int m=0;m<4;m++){
        int row = wr*64 + m*16 + cl;
        int sl  = ((4*kk + g) ^ (row & 7)) * 8;
        a[m] = *(const bf16x8*)&As_[row*64 + sl];
      }
      #pragma unroll
      for(int n=0;n<4;n++){
        int row = wc*64 + n*16 + cl;
        int sl  = ((4*kk + g) ^ (row & 7)) * 8;
        b[n] = *(const bf16x8*)&Bs_[row*64 + sl];
      }
      #pragma unroll
      for(int m=0;m<4;m++)
        #pragma unroll
        for(int n=0;n<4;n++)
          acc[m][n] = mfma_bf16(a[m], b[n], acc[m][n]);
    }
    __builtin_amdgcn_s_setprio(0);
    asm volatile("s_barrier" ::: "memory");
  }
  #pragma unroll
  for(int m=0;m<4;m++)
    #pragma unroll
    for(int n=0;n<4;n++)
      #pragma unroll
      for(int j=0;j<4;j++){
        int row = br + wr*64 + m*16 + g*4 + j;
        int col = bc + wc*64 + n*16 + cl;
        C[(size_t)row*N + col] = acc[m][n][j] + addsrc[(size_t)row*N + col];
      }
}

// ------- per-head RMSNorm (D=128) + RoPE; q additionally scaled by 1/sqrt(D) -------
__global__ void qk_norm_rope(const u16* __restrict__ qkv, const float* __restrict__ cosb,
                             const float* __restrict__ sinb, const float* __restrict__ qnw,
                             const float* __restrict__ knw,
                             u16* __restrict__ qb, u16* __restrict__ kb)
{
  __shared__ float red[2];
  __shared__ float buf[128];
  int bt = blockIdx.x;             // b*T + t
  int head = blockIdx.y;           // 0..39 : 32 q heads then 8 kv heads
  int d = threadIdx.x;             // 0..127
  int b = bt >> 10, t = bt & 1023;
  bool isq = head < NH;
  const u16* src = qkv + (size_t)bt*6144 + (isq ? head*DH : 4096 + (head-NH)*DH);
  float v = bf2f(src[d]);
  float ss = v*v;
  #pragma unroll
  for(int o=32;o>0;o>>=1) ss += __shfl_xor(ss, o);
  if((threadIdx.x & 63) == 0) red[threadIdx.x >> 6] = ss;
  __syncthreads();
  float tot = red[0] + red[1];
  float r = rsqrtf(tot * (1.0f/DH) + 1e-6f);
  float nv = v * r * (isq ? qnw[d] : knw[d]);
  buf[d] = nv;
  __syncthreads();
  float rot = (d < 64) ? -buf[d+64] : buf[d-64];
  float cs = cosb[(size_t)bt*DH + d], sn = sinb[(size_t)bt*DH + d];
  float ov = nv*cs + rot*sn;
  if(isq) ov *= 0.08838834764831845f;   // fold 1/sqrt(128) into q
  if(isq) qb[(((size_t)b*NH  + head)     *TSEQ + t)*DH + d] = f2bf(ov);
  else    kb[(((size_t)b*NKV + (head-NH))*TSEQ + t)*DH + d] = f2bf(ov);
}

// ---- flash attention: gload_lds + T2-swizzled K/V, ones-col l, defer-max ----------
__global__ __launch_bounds__(256) void attn_kernel(const u16* __restrict__ qb,
                                                   const u16* __restrict__ kb,
                                                   const u16* __restrict__ vt,
                                                   u16* __restrict__ aob)
{
  __shared__ u16 Ks[64*128];        // linear [64][128], slot^(row&7) swizzled (16B slots)
  __shared__ u16 Vs[144*64];        // linear [144][64]; rows 128..143 static (ones row @128)
  __shared__ u16 Ps[4][32][72];     // per-wave P tile [qrow][kv], pad 8
  int tid = threadIdx.x;
  int w = tid>>6, lane = tid&63, g = lane>>4, cl = lane&15;
  int nwg = gridDim.x * gridDim.y * gridDim.z;
  int orig = (blockIdx.z * gridDim.y + blockIdx.y) * gridDim.x + blockIdx.x;
  int wgid = xcd_swz(orig, nwg);
  int bxs = wgid % gridDim.x;
  int bys = (wgid / gridDim.x) % gridDim.y;
  int bzs = wgid / (gridDim.x * gridDim.y);
  int b = bzs, kvh = bys;
  int qt = (gridDim.x - 1) - bxs;     // big tiles first
  int q0 = qt*32;
  int h = kvh*4 + w;
  const u16* qp = qb + (((size_t)b*NH  + h  )*TSEQ)*DH;
  const u16* kp = kb + (((size_t)b*NKV + kvh)*TSEQ)*DH;
  const u16* vp = vt + (((size_t)b*NKV + kvh)*DH)*TSEQ;
  // static ones/zero rows 128..143 of Vs (row 128 = 1.0, rest 0); row128&7==0 -> identity swz
  for(int idx = tid; idx < 16*64; idx += 256){
    int r = idx >> 6, c2 = idx & 63;
    Vs[(128 + r)*64 + c2] = (r == 0) ? (u16)0x3F80 : (u16)0;
  }
  // per-thread staging geometry (fixed): K row=c>>4 slot=c&15; V row=c>>3 slot=c&7
  int kRow[4], kDst[4], kSrc[4], vRow[4], vDst[4], vSrc[4];
  #pragma unroll
  for(int it=0; it<4; it++){
    int c = tid + it*256;
    kRow[it] = c >> 4;
    int ks = c & 15;
    kDst[it] = kRow[it]*128 + ks*8;
    kSrc[it] = (ks ^ (kRow[it] & 7)) * 8;
    vRow[it] = c >> 3;
    int vs = c & 7;
    vDst[it] = vRow[it]*64 + vs*8;
    vSrc[it] = (vs ^ (vRow[it] & 7)) * 8;
  }
  bf16x8 aq[2][4];
  #pragma unroll
  for(int m=0;m<2;m++)
    #pragma unroll
    for(int kd=0;kd<4;kd++)
      aq[m][kd] = *(const bf16x8*)(qp + (size_t)(q0 + m*16 + cl)*DH + kd*32 + g*8);
  f32x4 accO[2][9];
  #pragma unroll
  for(int m=0;m<2;m++)
    #pragma unroll
    for(int n=0;n<9;n++) accO[m][n] = (f32x4){0.f,0.f,0.f,0.f};
  float mr[2][4];
  #pragma unroll
  for(int m=0;m<2;m++)
    #pragma unroll
    for(int j=0;j<4;j++) mr[m][j] = -1e30f;
  for(int kv0 = 0; kv0 < q0 + 32; kv0 += 64){
    // stage K 64x128 and V^T 128x64 via global_load_lds (linear dest, swizzled source)
    #pragma unroll
    for(int it=0; it<4; it++){
      GLOAD_LDS16(kp + (size_t)(kv0 + kRow[it])*DH + kSrc[it], &Ks[kDst[it]]);
      GLOAD_LDS16(vp + (size_t)vRow[it]*TSEQ + kv0 + vSrc[it], &Vs[vDst[it]]);
    }
    __syncthreads();
    f32x4 sc[2][4];
    #pragma unroll
    for(int m=0;m<2;m++)
      #pragma unroll
      for(int n=0;n<4;n++) sc[m][n] = (f32x4){0.f,0.f,0.f,0.f};
    __builtin_amdgcn_s_setprio(1);
    #pragma unroll
    for(int kd=0;kd<4;kd++){
      bf16x8 bk[4];
      #pragma unroll
      for(int n=0;n<4;n++){
        int row = n*16 + cl;                      // row&7 == cl&7
        bk[n] = *(const bf16x8*)&Ks[row*128 + (((kd*4 + g) ^ (cl & 7))*8)];
      }
      #pragma unroll
      for(int m=0;m<2;m++)
        #pragma unroll
        for(int n=0;n<4;n++)
          sc[m][n] = mfma_bf16(aq[m][kd], bk[n], sc[m][n]);
    }
    __builtin_amdgcn_s_setprio(0);
    // causal mask only on the diagonal tile
    if(kv0 + 63 > q0){
      #pragma unroll
      for(int m=0;m<2;m++)
        #pragma unroll
        for(int n=0;n<4;n++)
          #pragma unroll
          for(int j=0;j<4;j++){
            int row = q0 + m*16 + g*4 + j;
            int col = kv0 + n*16 + cl;
            if(col > row) sc[m][n][j] = -1e30f;
          }
    }
    // row max over this tile
    float tmax[2][4];
    #pragma unroll
    for(int m=0;m<2;m++)
      #pragma unroll
      for(int j=0;j<4;j++)
        tmax[m][j] = fmaxf(fmaxf(sc[m][0][j], sc[m][1][j]), fmaxf(sc[m][2][j], sc[m][3][j]));
    #pragma unroll
    for(int o=1;o<16;o<<=1)
      #pragma unroll
      for(int m=0;m<2;m++)
        #pragma unroll
        for(int j=0;j<4;j++) tmax[m][j] = fmaxf(tmax[m][j], __shfl_xor(tmax[m][j], o));
    // wave-uniform defer-max decision (THR=8)
    float grow = -1e30f;
    #pragma unroll
    for(int m=0;m<2;m++)
      #pragma unroll
      for(int j=0;j<4;j++) grow = fmaxf(grow, tmax[m][j] - mr[m][j]);
    grow = fmaxf(grow, __shfl_xor(grow, 16));
    grow = fmaxf(grow, __shfl_xor(grow, 32));
    if(grow > 8.0f){
      #pragma unroll
      for(int m=0;m<2;m++)
        #pragma unroll
        for(int j=0;j<4;j++){
          float mn = fmaxf(mr[m][j], tmax[m][j]);
          float f  = __expf(mr[m][j] - mn);
          mr[m][j] = mn;
          #pragma unroll
          for(int n=0;n<9;n++) accO[m][n][j] *= f;
        }
    }
    // exp
    #pragma unroll
    for(int m=0;m<2;m++)
      #pragma unroll
      for(int n=0;n<4;n++)
        #pragma unroll
        for(int j=0;j<4;j++)
          sc[m][n][j] = __expf(sc[m][n][j] - mr[m][j]);
    // write P to per-wave LDS
    #pragma unroll
    for(int m=0;m<2;m++)
      #pragma unroll
      for(int n=0;n<4;n++)
        #pragma unroll
        for(int j=0;j<4;j++)
          Ps[w][m*16 + g*4 + j][n*16 + cl] = f2bf(sc[m][n][j]);
    bf16x8 pa[2][2];
    #pragma unroll
    for(int m=0;m<2;m++)
      #pragma unroll
      for(int s2=0;s2<2;s2++)
        pa[m][s2] = *(const bf16x8*)&Ps[w][m*16 + cl][s2*32 + g*8];
    // PV (+ ones-column tile n=8 accumulating row-sum l); V rows swizzled by cl&7
    __builtin_amdgcn_s_setprio(1);
    #pragma unroll
    for(int n=0;n<9;n++){
      #pragma unroll
      for(int s2=0;s2<2;s2++){
        bf16x8 bv = *(const bf16x8*)&Vs[(n*16 + cl)*64 + (((s2*4 + g) ^ (cl & 7))*8)];
        #pragma unroll
        for(int m=0;m<2;m++)
          accO[m][n] = mfma_bf16(pa[m][s2], bv, accO[m][n]);
      }
    }
    __builtin_amdgcn_s_setprio(0);
    __syncthreads();
  }
  // epilogue: l lives in accO[m][8], col 0 (lane cl=0 of each g-group)
  #pragma unroll
  for(int m=0;m<2;m++){
    float linv[4];
    #pragma unroll
    for(int j=0;j<4;j++){
      float l = __shfl(accO[m][8][j], lane & 48);
      linv[j] = 1.0f / l;
    }
    #pragma unroll
    for(int n=0;n<8;n++)
      #pragma unroll
      for(int j=0;j<4;j++){
        int row = q0 + m*16 + g*4 + j;
        float v = accO[m][n][j] * linv[j];
        aob[((size_t)b*TSEQ + row)*(NH*DH) + h*DH + n*16 + cl] = f2bf(v);
      }
  }
}

// ---------------- routing: fp32 h2f + coalesced gwT, softmax, top-2, bucket --------
__global__ void route_kernel(const float* __restrict__ h2f, const float* __restrict__ gwT,
                             int* __restrict__ cnt, int* __restrict__ bidx,
                             float* __restrict__ bw)
{
  int lane = threadIdx.x & 63;
  int token = blockIdx.x*4 + (threadIdx.x >> 6);
  float acc[8];
  #pragma unroll
  for(int e=0;e<8;e++) acc[e]=0.f;
  for(int c0 = lane*4; c0 < CDIM; c0 += 256){
    float4 hv = *(const float4*)(h2f + (size_t)token*CDIM + c0);
    #pragma unroll
    for(int e=0;e<8;e++){
      float4 gv = *(const float4*)(gwT + (size_t)e*CDIM + c0);
      acc[e] += hv.x*gv.x + hv.y*gv.y + hv.z*gv.z + hv.w*gv.w;
    }
  }
  #pragma unroll
  for(int o=32;o>0;o>>=1)
    #pragma unroll
    for(int e=0;e<8;e++) acc[e] += __shfl_xor(acc[e], o);
  if(lane==0){
    float mx = acc[0];
    #pragma unroll
    for(int e=1;e<8;e++) mx = fmaxf(mx, acc[e]);
    float rw[8]; float s=0.f;
    #pragma unroll
    for(int e=0;e<8;e++){ rw[e] = __expf(acc[e]-mx); s += rw[e]; }
    #pragma unroll
    for(int e=0;e<8;e++) rw[e] /= s;
    int i0=0;
    #pragma unroll
    for(int e=1;e<8;e++) if(rw[e] > rw[i0]) i0=e;
    int i1 = (i0==0)?1:0;
    #pragma unroll
    for(int e=0;e<8;e++) if(e!=i0 && rw[e] > rw[i1]) i1=e;
    float tw0=rw[i0], tw1=rw[i1];
    float s1 = tw0+tw1+1e-9f;
    float a0 = tw0/s1, a1 = tw1/s1;
    float s2 = a0+a1+1e-9f;
    float w0 = a0/s2, w1 = a1/s2;
    int sl0 = atomicAdd(&cnt[i0],1);
    bidx[i0*CAP + sl0] = token; bw[i0*CAP + sl0] = w0;
    int sl1 = atomicAdd(&cnt[i1],1);
    bidx[i1*CAP + sl1] = token; bw[i1*CAP + sl1] = w1;
  }
}

// ==== MoE gate_up pipelined 128x(64G+64U) GEMM, expert->XCD pinned, 64KB LDS =======
// grid 1536: e=d&7, j=d>>3: y=j/12 (row tile of 128 slots), x=j%12 (64-col tile).
// LDS elems: A[2][8192] @0, Bg[2][4096] @16384, Bu[2][4096] @24576. Total 64KB -> 2 blk/CU.
__global__ __launch_bounds__(256) void gemm_gateup_pipe(const u16* __restrict__ h2b,
                                                        const u16* __restrict__ gupT,
                                                        u16* __restrict__ act,
                                                        const int* __restrict__ bidx,
                                                        const int* __restrict__ cnt)
{
  extern __shared__ u16 lds[];
  int d = blockIdx.x;
  int e = d & 7, j = d >> 3;
  int y = j / 12, x = j % 12;
  int nc = cnt[e];
  int sr = y*128;
  if(sr >= nc) return;
  const int K = CDIM, NT = K >> 6;
  const u16* Btg = gupT + (size_t)e*1536*CDIM + (size_t)(x*64)*CDIM;
  const u16* Btu = Btg + (size_t)768*CDIM;
  const int* be = bidx + e*CAP;
  int tid = threadIdx.x;
  int lane = tid&63, g = lane>>4, cl = lane&15;
  int w = tid>>6, wr = w>>1, wc = w&1;
  // A staging: 4 chunks/thread (128 rows x 8 slots); B staging: 2 chunks/thread (64 rows x 8 slots)
  int rowA[4], slotA[4], srcA[4];
  long long atok[4];
  #pragma unroll
  for(int l=0;l<4;l++){
    int c = l*256 + tid;
    rowA[l]  = c >> 3;
    slotA[l] = c & 7;
    srcA[l] = (slotA[l] ^ (rowA[l] & 7)) * 8;
    int t = be[sr + rowA[l]];
    if(t < 0 || t >= NTOK) t = 0;
    atok[l] = (long long)t * CDIM;
  }
  int rowB[2], slotB[2], srcB[2];
  #pragma unroll
  for(int l=0;l<2;l++){
    int c = l*256 + tid;
    rowB[l]  = c >> 3;
    slotB[l] = c & 7;
    srcB[l] = (slotB[l] ^ (rowB[l] & 7)) * 8;
  }
  f32x4 accG[4][2], accU[4][2];
  #pragma unroll
  for(int m=0;m<4;m++)
    #pragma unroll
    for(int n=0;n<2;n++){ accG[m][n] = (f32x4){0.f,0.f,0.f,0.f}; accU[m][n] = (f32x4){0.f,0.f,0.f,0.f}; }

  auto stage = [&](int t, int b){
    int k0 = t << 6;
    #pragma unroll
    for(int l=0;l<4;l++)
      GLOAD_LDS16(h2b + atok[l] + k0 + srcA[l],
                  &lds[b*8192 + rowA[l]*64 + slotA[l]*8]);
    #pragma unroll
    for(int l=0;l<2;l++)
      GLOAD_LDS16(Btg + (size_t)rowB[l]*K + k0 + srcB[l],
                  &lds[16384 + b*4096 + rowB[l]*64 + slotB[l]*8]);
    #pragma unroll
    for(int l=0;l<2;l++)
      GLOAD_LDS16(Btu + (size_t)rowB[l]*K + k0 + srcB[l],
                  &lds[24576 + b*4096 + rowB[l]*64 + slotB[l]*8]);
  };

  stage(0, 0);
  for(int t=0;t<NT;t++){
    int buf = t & 1;
    if(t+1 < NT){
      stage(t+1, buf^1);
      asm volatile("s_waitcnt vmcnt(8)" ::: "memory");
    } else {
      asm volatile("s_waitcnt vmcnt(0)" ::: "memory");
    }
    asm volatile("s_barrier" ::: "memory");
    const u16* As_ = &lds[buf*8192];
    const u16* Bg_ = &lds[16384 + buf*4096];
    const u16* Bu_ = &lds[24576 + buf*4096];
    __builtin_amdgcn_s_setprio(1);
    #pragma unroll
    for(int kk=0;kk<2;kk++){
      bf16x8 a[4], bg[2], bu[2];
      #pragma unroll
      for(int m=0;m<4;m++){
        int row = wr*64 + m*16 + cl;
        int sl  = ((4*kk + g) ^ (row & 7)) * 8;
        a[m] = *(const bf16x8*)&As_[row*64 + sl];
      }
      #pragma unroll
      for(int n=0;n<2;n++){
        int row = wc*32 + n*16 + cl;
        int sl  = ((4*kk + g) ^ (row & 7)) * 8;
        bg[n] = *(const bf16x8*)&Bg_[row*64 + sl];
        bu[n] = *(const bf16x8*)&Bu_[row*64 + sl];
      }
      #pragma unroll
      for(int m=0;m<4;m++)
        #pragma unroll
        for(int n=0;n<2;n++){
          accG[m][n] = mfma_bf16(a[m], bg[n], accG[m][n]);
          accU[m][n] = mfma_bf16(a[m], bu[n], accU[m][n]);
        }
    }
    __builtin_amdgcn_s_setprio(0);
    asm volatile("s_barrier" ::: "memory");
  }
  #pragma unroll
  for(int m=0;m<4;m++)
    #pragma unroll
    for(int n=0;n<2;n++)
      #pragma unroll
      for(int jj=0;jj<4;jj++){
        int slot = sr + wr*64 + m*16 + g*4 + jj;
        int col  = x*64 + wc*32 + n*16 + cl;
        float gv = accG[m][n][jj], uv = accU[m][n][jj];
        float av = gv / (1.f + __expf(-gv)) * uv;
        act[((size_t)e*CAP + slot)*FDIM + col] = f2bf(av);
      }
}

// ==== MoE down pipelined 128x128 GEMM, expert->XCD pinned, scatter-atomic ==========
__global__ __launch_bounds__(256) void gemm_down_pipe(const u16* __restrict__ act,
                                                      const u16* __restrict__ downT,
                                                      float* __restrict__ out,
                                                      const int* __restrict__ bidx,
                                                      const float* __restrict__ bw,
                                                      const int* __restrict__ cnt)
{
  extern __shared__ u16 lds[];
  int d = blockIdx.x;
  int e = d & 7, j = d >> 3;
  int y = j >> 4, x = j & 15;
  int nc = cnt[e];
  int sr = y*128;
  if(sr >= nc) return;
  const int K = FDIM, NT = K >> 6;   // 12 steps
  const u16* A  = act   + ((size_t)e*CAP + sr)*FDIM;
  const u16* Bt = downT + (size_t)e*CDIM*FDIM + (size_t)(x*128)*FDIM;
  const int* be = bidx + e*CAP;
  const float* bwe = bw + e*CAP;
  int tid = threadIdx.x;
  int lane = tid&63, g = lane>>4, cl = lane&15;
  int w = tid>>6, wr = w>>1, wc = w&1;
  int rowc[4], slotc[4], srcoff[4];
  #pragma unroll
  for(int l=0;l<4;l++){
    int c = l*256 + tid;
    rowc[l]  = c >> 3;
    slotc[l] = c & 7;
    srcoff[l] = (slotc[l] ^ (rowc[l] & 7)) * 8;
  }
  f32x4 acc[4][4];
  #pragma unroll
  for(int m=0;m<4;m++)
    #pragma unroll
    for(int n=0;n<4;n++) acc[m][n] = (f32x4){0.f,0.f,0.f,0.f};

  auto stage = [&](int t, int b){
    int k0 = t << 6;
    #pragma unroll
    for(int l=0;l<4;l++)
      GLOAD_LDS16(A + (size_t)rowc[l]*K + k0 + srcoff[l],
                  &lds[b*8192 + rowc[l]*64 + slotc[l]*8]);
    #pragma unroll
    for(int l=0;l<4;l++)
      GLOAD_LDS16(Bt + (size_t)rowc[l]*K + k0 + srcoff[l],
                  &lds[16384 + b*8192 + rowc[l]*64 + slotc[l]*8]);
  };

  stage(0, 0);
  for(int t=0;t<NT;t++){
    int buf = t & 1;
    if(t+1 < NT){
      stage(t+1, buf^1);
      asm volatile("s_waitcnt vmcnt(8)" ::: "memory");
    } else {
      asm volatile("s_waitcnt vmcnt(0)" ::: "memory");
    }
    asm volatile("s_barrier" ::: "memory");
    const u16* As_ = &lds[buf*8192];
    const u16* Bs_ = &lds[16384 + buf*8192];
    __builtin_amdgcn_s_setprio(1);
    #pragma unroll
    for(int kk=0;kk<2;kk++){
      bf16x8 a[4], b[4];
      #pragma unroll
      for(int m=0;m<4;m++){
        int row = wr*64 + m*16 + cl;
        int sl  = ((4*kk + g) ^ (row & 7)) * 8;
        a[m] = *(const bf16x8*)&As_[row*64 + sl];
      }
      #pragma unroll
      for(int n=0;n<4;n++){
        int row = wc*64 + n*16 + cl;
        int sl  = ((4*kk + g) ^ (row & 7)) * 8;
        b[n] = *(const bf16x8*)&Bs_[row*64 + sl];
      }
      #pragma unroll
      for(int m=0;m<4;m++)
        #pragma unroll
        for(int n=0;n<4;n++)
          acc[m][n] = mfma_bf16(a[m], b[n], acc[m][n]);
    }
    __builtin_amdgcn_s_setprio(0);
    asm volatile("s_barrier" ::: "memory");
  }
  #pragma unroll
  for(int m=0;m<4;m++)
    #pragma unroll
    for(int jj=0;jj<4;jj++){
      int slot = sr + wr*64 + m*16 + g*4 + jj;
      if(slot < nc){
        int tok = be[slot];
        float wgt = bwe[slot];
        #pragma unroll
        for(int n=0;n<4;n++){
          int col = x*128 + wc*64 + n*16 + cl;
          atomicAdd(out + (size_t)tok*CDIM + col, wgt * acc[m][n][jj]);
        }
      }
    }
}

// ------------------------------------ launch ---------------------------------------
extern "C" void kernel_launch(void* const* d_in, const int* in_sizes, int n_in,
                              void* d_out, int out_size, void* d_ws, size_t ws_size,
                              hipStream_t stream)
{
  const float* x     = (const float*)d_in[0];
  const float* cosb  = (const float*)d_in[1];
  const float* sinb  = (const float*)d_in[2];
  const float* ln1w  = (const float*)d_in[3];
  const float* qw    = (const float*)d_in[4];
  const float* kw    = (const float*)d_in[5];
  const float* vw    = (const float*)d_in[6];
  const float* ow    = (const float*)d_in[7];
  const float* qnw   = (const float*)d_in[8];
  const float* knw   = (const float*)d_in[9];
  const float* ln2w  = (const float*)d_in[10];
  const float* gatew = (const float*)d_in[11];
  const float* gupw  = (const float*)d_in[12];
  const float* downw = (const float*)d_in[13];
  float* out = (float*)d_out;

  char* ws = (char*)d_ws;
  size_t off = 0;
  auto alloc = [&](size_t bytes)->char*{
    char* p = ws + off;
    off = (off + bytes + 255) & ~(size_t)255;
    return p;
  };
  u16*   wqkvT = (u16*)  alloc((size_t)6144*2048*2);
  u16*   owT   = (u16*)  alloc((size_t)2048*4096*2);
  u16*   gupT  = (u16*)  alloc((size_t)8*1536*2048*2);
  u16*   downT = (u16*)  alloc((size_t)8*2048*768*2);
  u16*   h1b   = (u16*)  alloc((size_t)2048*2048*2);
  u16*   qkvb  = (u16*)  alloc((size_t)2048*6144*2);
  u16*   qb    = (u16*)  alloc((size_t)2*32*1024*128*2);
  u16*   kb    = (u16*)  alloc((size_t)2*8*1024*128*2);
  u16*   vt    = (u16*)  alloc((size_t)2*8*1024*128*2);
  u16*   aob   = (u16*)  alloc((size_t)2048*4096*2);
  float* h2f   = (float*)alloc((size_t)2048*2048*4);
  u16*   h2b   = (u16*)  alloc((size_t)2048*2048*2);
  u16*   actb  = (u16*)  alloc((size_t)8*2048*768*2);
  int*   bidx  = (int*)  alloc((size_t)8*2048*4);
  float* bwgt  = (float*)alloc((size_t)8*2048*4);
  float* gwT   = (float*)alloc((size_t)8*2048*4);
  int*   cnt   = (int*)  alloc(64);
  (void)ws_size; (void)in_sizes; (void)n_in; (void)out_size;

  hipMemsetAsync(cnt, 0, 8*sizeof(int), stream);

  // weight transposes/casts (64x64-tile, 16B r/w); q+k+v merged
  cast_transpose_qkv<<<dim3(96,32), 256, 0, stream>>>(qw, kw, vw, wqkvT);
  cast_transpose<<<dim3(32,64,1), 256, 0, stream>>>(ow, owT,      4096, 2048, 2048, 1, 0, 0);
  cast_transpose<<<dim3(24,32,8), 256, 0, stream>>>(gupw, gupT,   2048, 1536, 1536, 8, 0, (long long)2048*1536);
  cast_transpose<<<dim3(32,12,8), 256, 0, stream>>>(downw, downT, 768,  2048, 2048, 8, 0, (long long)768*2048);
  transpose_gate<<<64, 256, 0, stream>>>(gatew, gwT);

  // ln1 + cast
  rmsnorm_kernel<<<2048, 256, 0, stream>>>(x, ln1w, h1b, nullptr);
  // qkv = h @ [q|k|v]  (M=2048, N=6144, K=2048) -> bf16 ; 256x192 pipe, 256 blocks
  gemm256<<<dim3(32,8), 512, 114688, stream>>>(h1b, wqkvT, qkvb, 2048, 6144, 2048);
  // q/k: per-head rmsnorm + rope (+ q*scale) -> bf16
  qk_norm_rope<<<dim3(2048,40), 128, 0, stream>>>(qkvb, cosb, sinb, qnw, knw, qb, kb);
  // v -> (b,kv,D,T) bf16
  transpose_u16<<<dim3(4,32,16), 256, 0, stream>>>(qkvb + 5120, vt, 1024, 128, 6144, 8,
                                                   (long long)1024*6144, 128);
  // attention
  attn_kernel<<<dim3(32,8,2), 256, 0, stream>>>(qb, kb, vt, aob);
  // o-proj + residual -> out  (pipelined 128x128)
  gemm_oproj_pipe<<<256, 256, 65536, stream>>>(aob, owT, out, x, 2048, 2048, 4096);
  // ln2 (fp32 for router + bf16 for experts)
  rmsnorm_kernel<<<2048, 256, 0, stream>>>(out, ln2w, h2b, h2f);
  // routing (fp32 h2f + coalesced gwT)
  route_kernel<<<512, 256, 0, stream>>>(h2f, gwT, cnt, bidx, bwgt);
  // experts: pipelined, expert->XCD pinned; gate_up 128x(64G+64U), 64KB LDS, 2 blk/CU
  gemm_gateup_pipe<<<1536, 256, 65536, stream>>>(h2b, gupT, actb, bidx, cnt);
  gemm_down_pipe<<<2048, 256, 65536, stream>>>(actb, downT, out, bidx, bwgt, cnt);
}

// Round 26
// 431.257 us; speedup vs baseline: 1.0479x; 1.0273x over previous
//
#include <hip/hip_runtime.h>
#include <hip/hip_bf16.h>

typedef short bf16x8 __attribute__((ext_vector_type(8)));
typedef float f32x4 __attribute__((ext_vector_type(4)));
typedef unsigned short u16;

#define NTOK 2048
#define CDIM 2048
#define TSEQ 1024
#define NH   32
#define NKV  8
#define DH   128
#define NE   8
#define FDIM 768
#define CAP  2048

#define GLOAD_LDS16(g, l) \
  __builtin_amdgcn_global_load_lds((const __attribute__((address_space(1))) void*)(g), \
                                   (__attribute__((address_space(3))) void*)(l), 16, 0, 0)

__device__ __forceinline__ u16 f2bf(float f){
  union { float f; unsigned u; } v; v.f = f;
  unsigned r = v.u + 0x7FFFu + ((v.u >> 16) & 1u);
  return (u16)(r >> 16);
}
__device__ __forceinline__ float bf2f(u16 x){
  union { unsigned u; float f; } v; v.u = ((unsigned)x) << 16; return v.f;
}

__device__ __forceinline__ f32x4 mfma_bf16(bf16x8 a, bf16x8 b, f32x4 c){
  return __builtin_amdgcn_mfma_f32_16x16x32_bf16(a, b, c, 0, 0, 0);
}

// bijective XCD-chunk swizzle (m204): orig linear id -> chunked id
__device__ __forceinline__ int xcd_swz(int orig, int nwg){
  int xcd = orig & 7;
  int q = nwg >> 3, r = nwg & 7;
  int base = (xcd < r) ? xcd*(q+1) : r*(q+1) + (xcd-r)*q;
  return base + (orig >> 3);
}

// ---- fast transpose + fp32->bf16 cast, 64x64 tile: out[c][r] = in[r][c] -----------
__global__ void cast_transpose(const float* __restrict__ in, u16* __restrict__ out,
                               int R, int Cc, int rstride, int d1,
                               long long s_hi, long long s_lo)
{
  __shared__ u16 tile[64][72];
  int z = blockIdx.z;
  in  += (long long)(z / d1) * s_hi + (long long)(z % d1) * s_lo;
  out += (size_t)z * R * Cc;
  int r0 = blockIdx.y*64, c0 = blockIdx.x*64;
  int lr = threadIdx.x >> 4;          // 0..15
  int lc = (threadIdx.x & 15) * 4;    // 0..60
  #pragma unroll
  for(int i=0;i<4;i++){
    int r = lr + i*16;
    float4 v = *(const float4*)(in + (size_t)(r0 + r)*rstride + c0 + lc);
    tile[lc+0][r] = f2bf(v.x);
    tile[lc+1][r] = f2bf(v.y);
    tile[lc+2][r] = f2bf(v.z);
    tile[lc+3][r] = f2bf(v.w);
  }
  __syncthreads();
  int oc  = threadIdx.x >> 2;         // 0..63
  int orr = (threadIdx.x & 3) * 16;   // 0,16,32,48
  uint4 a  = *(const uint4*)&tile[oc][orr];
  uint4 b2 = *(const uint4*)&tile[oc][orr + 8];
  *(uint4*)(out + (size_t)(c0+oc)*R + r0 + orr)     = a;
  *(uint4*)(out + (size_t)(c0+oc)*R + r0 + orr + 8) = b2;
}

// ---- merged qkv weight transpose: x<64 -> q, x<80 -> k, else v --------------------
__global__ void cast_transpose_qkv(const float* __restrict__ qw, const float* __restrict__ kw,
                                   const float* __restrict__ vw, u16* __restrict__ wqkvT)
{
  __shared__ u16 tile[64][72];
  int bx = blockIdx.x;
  const float* in; u16* out; int rstride, c0;
  if(bx < 64){       in = qw; out = wqkvT;                        rstride = 4096; c0 = bx*64; }
  else if(bx < 80){  in = kw; out = wqkvT + (size_t)4096*2048;    rstride = 1024; c0 = (bx-64)*64; }
  else {             in = vw; out = wqkvT + (size_t)5120*2048;    rstride = 1024; c0 = (bx-80)*64; }
  const int R = 2048;
  int r0 = blockIdx.y*64;
  int lr = threadIdx.x >> 4;
  int lc = (threadIdx.x & 15) * 4;
  #pragma unroll
  for(int i=0;i<4;i++){
    int r = lr + i*16;
    float4 v = *(const float4*)(in + (size_t)(r0 + r)*rstride + c0 + lc);
    tile[lc+0][r] = f2bf(v.x);
    tile[lc+1][r] = f2bf(v.y);
    tile[lc+2][r] = f2bf(v.z);
    tile[lc+3][r] = f2bf(v.w);
  }
  __syncthreads();
  int oc  = threadIdx.x >> 2;
  int orr = (threadIdx.x & 3) * 16;
  uint4 a  = *(const uint4*)&tile[oc][orr];
  uint4 b2 = *(const uint4*)&tile[oc][orr + 8];
  *(uint4*)(out + (size_t)(c0+oc)*R + r0 + orr)     = a;
  *(uint4*)(out + (size_t)(c0+oc)*R + r0 + orr + 8) = b2;
}

// ---- tiny transpose: gwT[e][c] = gw[c][e]  (2048x8 -> 8x2048 fp32) ----------------
__global__ void transpose_gate(const float* __restrict__ gw, float* __restrict__ gwT)
{
  int i = blockIdx.x*256 + threadIdx.x;      // 16384 elems
  int c = i >> 3, e = i & 7;
  gwT[(size_t)e*CDIM + c] = gw[(size_t)c*NE + e];
}

// ---------------- transpose bf16->bf16: out[c][r] = in[r][c] -----------------------
__global__ void transpose_u16(const u16* __restrict__ in, u16* __restrict__ out,
                              int R, int Cc, int rstride, int d1,
                              long long s_hi, long long s_lo)
{
  __shared__ u16 tile[32][34];
  int z = blockIdx.z;
  in += (long long)(z / d1) * s_hi + (long long)(z % d1) * s_lo;
  out += (size_t)z * R * Cc;
  int tx = threadIdx.x & 31, ty = threadIdx.x >> 5;   // 32 x 8
  int r0 = blockIdx.y * 32, c0 = blockIdx.x * 32;
  #pragma unroll
  for(int i=0;i<4;i++){
    int r = r0 + ty + i*8;
    if(r < R && c0 + tx < Cc) tile[ty + i*8][tx] = in[(size_t)r * rstride + c0 + tx];
  }
  __syncthreads();
  #pragma unroll
  for(int i=0;i<4;i++){
    int c = c0 + ty + i*8;
    if(c < Cc && r0 + tx < R) out[(size_t)c * R + r0 + tx] = tile[tx][ty + i*8];
  }
}

// ---------------- RMSNorm over C=2048, write bf16 (+ optional fp32) ----------------
__global__ void rmsnorm_kernel(const float* __restrict__ x, const float* __restrict__ w,
                               u16* __restrict__ outb, float* __restrict__ outf)
{
  __shared__ float sbuf[4];
  int row = blockIdx.x;
  const float* xr = x + (size_t)row * CDIM;
  int t0 = threadIdx.x * 8;
  float4 v0 = *(const float4*)(xr + t0);
  float4 v1 = *(const float4*)(xr + t0 + 4);
  float a[8] = {v0.x,v0.y,v0.z,v0.w,v1.x,v1.y,v1.z,v1.w};
  float ss = 0.f;
  #pragma unroll
  for(int i=0;i<8;i++) ss += a[i]*a[i];
  #pragma unroll
  for(int o=32;o>0;o>>=1) ss += __shfl_xor(ss, o);
  if((threadIdx.x & 63) == 0) sbuf[threadIdx.x >> 6] = ss;
  __syncthreads();
  float tot = sbuf[0]+sbuf[1]+sbuf[2]+sbuf[3];
  float r = rsqrtf(tot * (1.0f/CDIM) + 1e-6f);
  float4 w0 = *(const float4*)(w + t0);
  float4 w1 = *(const float4*)(w + t0 + 4);
  float wv[8] = {w0.x,w0.y,w0.z,w0.w,w1.x,w1.y,w1.z,w1.w};
  #pragma unroll
  for(int i=0;i<8;i++){
    float o = a[i] * r * wv[i];
    outb[(size_t)row*CDIM + t0 + i] = f2bf(o);
    if(outf) outf[(size_t)row*CDIM + t0 + i] = o;
  }
}

// ======== deep-pipelined 256x192 GEMM (T2+T3+T4+T5): Cb[bf16] = A @ Bt^T ===========
__global__ __launch_bounds__(512, 1) void gemm256(const u16* __restrict__ A,
                                                  const u16* __restrict__ Bt,
                                                  u16* __restrict__ Cb,
                                                  int M, int N, int K)
{
  extern __shared__ u16 lds[];
  const int NT = K >> 6;
  int tid = threadIdx.x;
  int lane = tid & 63, g = lane >> 4, cl = lane & 15;
  int wid = tid >> 6, wr = wid >> 2, wc = wid & 3;
  int br = blockIdx.y * 256, bc = blockIdx.x * 192;
  int rowl[4], slotl[4], srcoff[4];
  #pragma unroll
  for(int l=0;l<4;l++){
    int c = l*512 + tid;
    rowl[l]  = c >> 3;
    slotl[l] = c & 7;
    srcoff[l] = (slotl[l] ^ (rowl[l] & 7)) * 8;   // pre-swizzled global col (elems)
  }
  f32x4 acc[8][3];
  #pragma unroll
  for(int m=0;m<8;m++)
    #pragma unroll
    for(int n=0;n<3;n++) acc[m][n] = (f32x4){0.f,0.f,0.f,0.f};

  auto stage = [&](int t, int b){
    int k0 = t << 6;
    #pragma unroll
    for(int l=0;l<4;l++)
      GLOAD_LDS16(A  + (size_t)(br + rowl[l])*K + k0 + srcoff[l],
                  &lds[b*16384 + rowl[l]*64 + slotl[l]*8]);
    #pragma unroll
    for(int l=0;l<3;l++)
      GLOAD_LDS16(Bt + (size_t)(bc + rowl[l])*K + k0 + srcoff[l],
                  &lds[32768 + b*12288 + rowl[l]*64 + slotl[l]*8]);
  };

  stage(0, 0);
  for(int t=0;t<NT;t++){
    int buf = t & 1;
    if(t+1 < NT){
      stage(t+1, buf^1);
      asm volatile("s_waitcnt vmcnt(7)" ::: "memory");
    } else {
      asm volatile("s_waitcnt vmcnt(0)" ::: "memory");
    }
    asm volatile("s_barrier" ::: "memory");
    const u16* As_ = &lds[buf*16384];
    const u16* Bs_ = &lds[32768 + buf*12288];
    __builtin_amdgcn_s_setprio(1);
    #pragma unroll
    for(int kk=0;kk<2;kk++){
      bf16x8 a[8], b[3];
      #pragma unroll
      for(int m=0;m<8;m++){
        int row = wr*128 + m*16 + cl;
        int sl  = ((4*kk + g) ^ (row & 7)) * 8;
        a[m] = *(const bf16x8*)&As_[row*64 + sl];
      }
      #pragma unroll
      for(int n=0;n<3;n++){
        int row = wc*48 + n*16 + cl;
        int sl  = ((4*kk + g) ^ (row & 7)) * 8;
        b[n] = *(const bf16x8*)&Bs_[row*64 + sl];
      }
      #pragma unroll
      for(int m=0;m<8;m++)
        #pragma unroll
        for(int n=0;n<3;n++)
          acc[m][n] = mfma_bf16(a[m], b[n], acc[m][n]);
    }
    __builtin_amdgcn_s_setprio(0);
    asm volatile("s_barrier" ::: "memory");
  }
  #pragma unroll
  for(int m=0;m<8;m++)
    #pragma unroll
    for(int n=0;n<3;n++)
      #pragma unroll
      for(int j=0;j<4;j++){
        int row = br + wr*128 + m*16 + g*4 + j;
        int col = bc + wc*48 + n*16 + cl;
        Cb[(size_t)row*N + col] = f2bf(acc[m][n][j]);
      }
}

// ======== o-proj pipelined 128x128 GEMM: out[fp32] = A @ Bt^T + addsrc ==============
__global__ __launch_bounds__(256) void gemm_oproj_pipe(const u16* __restrict__ A,
                                                       const u16* __restrict__ Bt,
                                                       float* __restrict__ C,
                                                       const float* __restrict__ addsrc,
                                                       int M, int N, int K)
{
  extern __shared__ u16 lds[];
  int nwg = gridDim.x;
  int wgid = xcd_swz(blockIdx.x, nwg);
  int nbx = N >> 7;
  int bys = wgid / nbx, bxs = wgid % nbx;
  const int NT = K >> 6;
  int tid = threadIdx.x;
  int lane = tid&63, g = lane>>4, cl = lane&15;
  int w = tid>>6, wr = w>>1, wc = w&1;
  int br = bys*128, bc = bxs*128;
  int rowc[4], slotc[4], srcoff[4];
  #pragma unroll
  for(int l=0;l<4;l++){
    int c = l*256 + tid;
    rowc[l]  = c >> 3;
    slotc[l] = c & 7;
    srcoff[l] = (slotc[l] ^ (rowc[l] & 7)) * 8;
  }
  f32x4 acc[4][4];
  #pragma unroll
  for(int m=0;m<4;m++)
    #pragma unroll
    for(int n=0;n<4;n++) acc[m][n] = (f32x4){0.f,0.f,0.f,0.f};

  auto stage = [&](int t, int b){
    int k0 = t << 6;
    #pragma unroll
    for(int l=0;l<4;l++)
      GLOAD_LDS16(A + (size_t)(br + rowc[l])*K + k0 + srcoff[l],
                  &lds[b*8192 + rowc[l]*64 + slotc[l]*8]);
    #pragma unroll
    for(int l=0;l<4;l++)
      GLOAD_LDS16(Bt + (size_t)(bc + rowc[l])*K + k0 + srcoff[l],
                  &lds[16384 + b*8192 + rowc[l]*64 + slotc[l]*8]);
  };

  stage(0, 0);
  for(int t=0;t<NT;t++){
    int buf = t & 1;
    if(t+1 < NT){
      stage(t+1, buf^1);
      asm volatile("s_waitcnt vmcnt(8)" ::: "memory");
    } else {
      asm volatile("s_waitcnt vmcnt(0)" ::: "memory");
    }
    asm volatile("s_barrier" ::: "memory");
    const u16* As_ = &lds[buf*8192];
    const u16* Bs_ = &lds[16384 + buf*8192];
    __builtin_amdgcn_s_setprio(1);
    #pragma unroll
    for(int kk=0;kk<2;kk++){
      bf16x8 a[4], b[4];
      #pragma unroll
      for(int m=0;m<4;m++){
        int row = wr*64 + m*16 + cl;
        int sl  = ((4*kk + g) ^ (row & 7)) * 8;
        a[m] = *(const bf16x8*)&As_[row*64 + sl];
      }
      #pragma unroll
      for(int n=0;n<4;n++){
        int row = wc*64 + n*16 + cl;
        int sl  = ((4*kk + g) ^ (row & 7)) * 8;
        b[n] = *(const bf16x8*)&Bs_[row*64 + sl];
      }
      #pragma unroll
      for(int m=0;m<4;m++)
        #pragma unroll
        for(int n=0;n<4;n++)
          acc[m][n] = mfma_bf16(a[m], b[n], acc[m][n]);
    }
    __builtin_amdgcn_s_setprio(0);
    asm volatile("s_barrier" ::: "memory");
  }
  #pragma unroll
  for(int m=0;m<4;m++)
    #pragma unroll
    for(int n=0;n<4;n++)
      #pragma unroll
      for(int j=0;j<4;j++){
        int row = br + wr*64 + m*16 + g*4 + j;
        int col = bc + wc*64 + n*16 + cl;
        C[(size_t)row*N + col] = acc[m][n][j] + addsrc[(size_t)row*N + col];
      }
}

// ------- per-head RMSNorm (D=128) + RoPE; q additionally scaled by 1/sqrt(D) -------
__global__ void qk_norm_rope(const u16* __restrict__ qkv, const float* __restrict__ cosb,
                             const float* __restrict__ sinb, const float* __restrict__ qnw,
                             const float* __restrict__ knw,
                             u16* __restrict__ qb, u16* __restrict__ kb)
{
  __shared__ float red[2];
  __shared__ float buf[128];
  int bt = blockIdx.x;             // b*T + t
  int head = blockIdx.y;           // 0..39 : 32 q heads then 8 kv heads
  int d = threadIdx.x;             // 0..127
  int b = bt >> 10, t = bt & 1023;
  bool isq = head < NH;
  const u16* src = qkv + (size_t)bt*6144 + (isq ? head*DH : 4096 + (head-NH)*DH);
  float v = bf2f(src[d]);
  float ss = v*v;
  #pragma unroll
  for(int o=32;o>0;o>>=1) ss += __shfl_xor(ss, o);
  if((threadIdx.x & 63) == 0) red[threadIdx.x >> 6] = ss;
  __syncthreads();
  float tot = red[0] + red[1];
  float r = rsqrtf(tot * (1.0f/DH) + 1e-6f);
  float nv = v * r * (isq ? qnw[d] : knw[d]);
  buf[d] = nv;
  __syncthreads();
  float rot = (d < 64) ? -buf[d+64] : buf[d-64];
  float cs = cosb[(size_t)bt*DH + d], sn = sinb[(size_t)bt*DH + d];
  float ov = nv*cs + rot*sn;
  if(isq) ov *= 0.08838834764831845f;   // fold 1/sqrt(128) into q
  if(isq) qb[(((size_t)b*NH  + head)     *TSEQ + t)*DH + d] = f2bf(ov);
  else    kb[(((size_t)b*NKV + (head-NH))*TSEQ + t)*DH + d] = f2bf(ov);
}

// ---- flash attention, paired q-tiles (p, 31-p): 8 waves (4 heads x 2 halves),
// ---- double-buffered K/V via gload_lds + counted vmcnt, T2 swizzle, ones-col l ----
// LDS elems: Ks[2][8192]@0, Vs[2][9216]@16384, Ps[8][16][72]@34816  (88064 B)
__global__ __launch_bounds__(512) void attn_kernel(const u16* __restrict__ qb,
                                                   const u16* __restrict__ kb,
                                                   const u16* __restrict__ vt,
                                                   u16* __restrict__ aob)
{
  extern __shared__ u16 lds[];
  int tid = threadIdx.x;
  int w = tid>>6, lane = tid&63, g = lane>>4, cl = lane&15;
  int nwg = gridDim.x * gridDim.y * gridDim.z;   // 256
  int orig = (blockIdx.z * gridDim.y + blockIdx.y) * gridDim.x + blockIdx.x;
  int wgid = xcd_swz(orig, nwg);
  int bxs = wgid % gridDim.x;                    // pair index 0..15
  int bys = (wgid / gridDim.x) % gridDim.y;      // kvh
  int bzs = wgid / (gridDim.x * gridDim.y);      // b
  int b = bzs, kvh = bys, pr = bxs;
  int head = kvh*4 + (w>>1);
  int mh = w & 1;                                 // 16-row half within the 32-row tile
  const u16* qp = qb + (((size_t)b*NH  + head)*TSEQ)*DH;
  const u16* kp = kb + (((size_t)b*NKV + kvh)*TSEQ)*DH;
  const u16* vp = vt + (((size_t)b*NKV + kvh)*DH)*TSEQ;
  u16* Psw = &lds[34816 + w*16*72];
  // static ones/zero rows 128..143 of BOTH Vs buffers (row 128 = 1.0, rest 0)
  for(int idx = tid; idx < 2*16*64; idx += 512){
    int bufi = idx >> 10, rr = (idx >> 6) & 15, c2 = idx & 63;
    lds[16384 + bufi*9216 + (128 + rr)*64 + c2] = (rr == 0) ? (u16)0x3F80 : (u16)0;
  }
  __syncthreads();
  // staging geometry: 2 K chunks + 2 V chunks per thread (512 thr x 2 = 1024 chunks each)
  int kRow[2], kDst[2], kSrc[2], vRow[2], vDst[2], vSrc[2];
  #pragma unroll
  for(int it=0; it<2; it++){
    int c = tid + it*512;
    kRow[it] = c >> 4;
    int ks = c & 15;
    kDst[it] = kRow[it]*128 + ks*8;
    kSrc[it] = (ks ^ (kRow[it] & 7)) * 8;
    vRow[it] = c >> 3;
    int vs = c & 7;
    vDst[it] = vRow[it]*64 + vs*8;
    vSrc[it] = (vs ^ (vRow[it] & 7)) * 8;
  }
  int qts[2] = { pr, 31 - pr };
  for(int ti=0; ti<2; ti++){
    int qt = qts[ti];
    int q0 = qt*32;
    int qr0 = q0 + mh*16;                         // this wave's 16 q-rows
    const int NTk = (q0 + 95) >> 6;               // kv-tiles for this q-tile
    bf16x8 aq[4];
    #pragma unroll
    for(int kd=0;kd<4;kd++)
      aq[kd] = *(const bf16x8*)(qp + (size_t)(qr0 + cl)*DH + kd*32 + g*8);
    f32x4 accO[9];
    #pragma unroll
    for(int n=0;n<9;n++) accO[n] = (f32x4){0.f,0.f,0.f,0.f};
    float mr[4];
    #pragma unroll
    for(int j=0;j<4;j++) mr[j] = -1e30f;
    // prologue: stage kv-tile 0 into buf 0
    #pragma unroll
    for(int it=0; it<2; it++){
      GLOAD_LDS16(kp + (size_t)kRow[it]*DH + kSrc[it], &lds[kDst[it]]);
      GLOAD_LDS16(vp + (size_t)vRow[it]*TSEQ + vSrc[it], &lds[16384 + vDst[it]]);
    }
    for(int t=0; t<NTk; t++){
      int buf = t & 1;
      int kv0 = t*64;
      if(t+1 < NTk){
        int kv1 = kv0 + 64, nb = buf ^ 1;
        #pragma unroll
        for(int it=0; it<2; it++){
          GLOAD_LDS16(kp + (size_t)(kv1 + kRow[it])*DH + kSrc[it], &lds[nb*8192 + kDst[it]]);
          GLOAD_LDS16(vp + (size_t)vRow[it]*TSEQ + kv1 + vSrc[it], &lds[16384 + nb*9216 + vDst[it]]);
        }
        asm volatile("s_waitcnt vmcnt(4)" ::: "memory");
      } else {
        asm volatile("s_waitcnt vmcnt(0)" ::: "memory");
      }
      asm volatile("s_barrier" ::: "memory");
      const u16* Ksb = &lds[buf*8192];
      const u16* Vsb = &lds[16384 + buf*9216];
      f32x4 sc[4];
      #pragma unroll
      for(int n=0;n<4;n++) sc[n] = (f32x4){0.f,0.f,0.f,0.f};
      __builtin_amdgcn_s_setprio(1);
      #pragma unroll
      for(int kd=0;kd<4;kd++){
        bf16x8 bk[4];
        #pragma unroll
        for(int n=0;n<4;n++){
          int row = n*16 + cl;                    // row&7 == cl&7
          bk[n] = *(const bf16x8*)&Ksb[row*128 + (((kd*4 + g) ^ (cl & 7))*8)];
        }
        #pragma unroll
        for(int n=0;n<4;n++)
          sc[n] = mfma_bf16(aq[kd], bk[n], sc[n]);
      }
      __builtin_amdgcn_s_setprio(0);
      // causal mask on diagonal tile(s)
      if(kv0 + 63 > q0){
        #pragma unroll
        for(int n=0;n<4;n++)
          #pragma unroll
          for(int j=0;j<4;j++){
            int row = qr0 + g*4 + j;
            int col = kv0 + n*16 + cl;
            if(col > row) sc[n][j] = -1e30f;
          }
      }
      // row max over this tile
      float tmax[4];
      #pragma unroll
      for(int j=0;j<4;j++)
        tmax[j] = fmaxf(fmaxf(sc[0][j], sc[1][j]), fmaxf(sc[2][j], sc[3][j]));
      #pragma unroll
      for(int o=1;o<16;o<<=1)
        #pragma unroll
        for(int j=0;j<4;j++) tmax[j] = fmaxf(tmax[j], __shfl_xor(tmax[j], o));
      // wave-uniform defer-max decision (THR=8)
      float grow = -1e30f;
      #pragma unroll
      for(int j=0;j<4;j++) grow = fmaxf(grow, tmax[j] - mr[j]);
      grow = fmaxf(grow, __shfl_xor(grow, 16));
      grow = fmaxf(grow, __shfl_xor(grow, 32));
      if(grow > 8.0f){
        #pragma unroll
        for(int j=0;j<4;j++){
          float mn = fmaxf(mr[j], tmax[j]);
          float f  = __expf(mr[j] - mn);
          mr[j] = mn;
          #pragma unroll
          for(int n=0;n<9;n++) accO[n][j] *= f;
        }
      }
      // exp
      #pragma unroll
      for(int n=0;n<4;n++)
        #pragma unroll
        for(int j=0;j<4;j++)
          sc[n][j] = __expf(sc[n][j] - mr[j]);
      // write P to per-wave LDS [16 rows][72]
      #pragma unroll
      for(int n=0;n<4;n++)
        #pragma unroll
        for(int j=0;j<4;j++)
          Psw[(g*4 + j)*72 + n*16 + cl] = f2bf(sc[n][j]);
      bf16x8 pa[2];
      #pragma unroll
      for(int s2=0;s2<2;s2++)
        pa[s2] = *(const bf16x8*)&Psw[cl*72 + s2*32 + g*8];
      // PV (+ ones-column tile n=8 accumulating row-sum l); V rows swizzled by cl&7
      __builtin_amdgcn_s_setprio(1);
      #pragma unroll
      for(int n=0;n<9;n++){
        #pragma unroll
        for(int s2=0;s2<2;s2++){
          bf16x8 bv = *(const bf16x8*)&Vsb[(n*16 + cl)*64 + (((s2*4 + g) ^ (cl & 7))*8)];
          accO[n] = mfma_bf16(pa[s2], bv, accO[n]);
        }
      }
      __builtin_amdgcn_s_setprio(0);
      asm volatile("s_barrier" ::: "memory");
    }
    // epilogue: l lives in accO[8], col 0 (lane cl=0 of each g-group)
    float linv[4];
    #pragma unroll
    for(int j=0;j<4;j++){
      float l = __shfl(accO[8][j], lane & 48);
      linv[j] = 1.0f / l;
    }
    #pragma unroll
    for(int n=0;n<8;n++)
      #pragma unroll
      for(int j=0;j<4;j++){
        int row = qr0 + g*4 + j;
        float v = accO[n][j] * linv[j];
        aob[((size_t)b*TSEQ + row)*(NH*DH) + head*DH + n*16 + cl] = f2bf(v);
      }
  }
}

// ---------------- routing: fp32 h2f + coalesced gwT, softmax, top-2, bucket --------
__global__ void route_kernel(const float* __restrict__ h2f, const float* __restrict__ gwT,
                             int* __restrict__ cnt, int* __restrict__ bidx,
                             float* __restrict__ bw)
{
  int lane = threadIdx.x & 63;
  int token = blockIdx.x*4 + (threadIdx.x >> 6);
  float acc[8];
  #pragma unroll
  for(int e=0;e<8;e++) acc[e]=0.f;
  for(int c0 = lane*4; c0 < CDIM; c0 += 256){
    float4 hv = *(const float4*)(h2f + (size_t)token*CDIM + c0);
    #pragma unroll
    for(int e=0;e<8;e++){
      float4 gv = *(const float4*)(gwT + (size_t)e*CDIM + c0);
      acc[e] += hv.x*gv.x + hv.y*gv.y + hv.z*gv.z + hv.w*gv.w;
    }
  }
  #pragma unroll
  for(int o=32;o>0;o>>=1)
    #pragma unroll
    for(int e=0;e<8;e++) acc[e] += __shfl_xor(acc[e], o);
  if(lane==0){
    float mx = acc[0];
    #pragma unroll
    for(int e=1;e<8;e++) mx = fmaxf(mx, acc[e]);
    float rw[8]; float s=0.f;
    #pragma unroll
    for(int e=0;e<8;e++){ rw[e] = __expf(acc[e]-mx); s += rw[e]; }
    #pragma unroll
    for(int e=0;e<8;e++) rw[e] /= s;
    int i0=0;
    #pragma unroll
    for(int e=1;e<8;e++) if(rw[e] > rw[i0]) i0=e;
    int i1 = (i0==0)?1:0;
    #pragma unroll
    for(int e=0;e<8;e++) if(e!=i0 && rw[e] > rw[i1]) i1=e;
    float tw0=rw[i0], tw1=rw[i1];
    float s1 = tw0+tw1+1e-9f;
    float a0 = tw0/s1, a1 = tw1/s1;
    float s2 = a0+a1+1e-9f;
    float w0 = a0/s2, w1 = a1/s2;
    int sl0 = atomicAdd(&cnt[i0],1);
    bidx[i0*CAP + sl0] = token; bw[i0*CAP + sl0] = w0;
    int sl1 = atomicAdd(&cnt[i1],1);
    bidx[i1*CAP + sl1] = token; bw[i1*CAP + sl1] = w1;
  }
}

// ==== MoE gate_up pipelined 128x(64G+64U) GEMM, expert->XCD pinned, 64KB LDS =======
// grid 1536: e=d&7, j=d>>3: y=j/12 (row tile of 128 slots), x=j%12 (64-col tile).
// LDS elems: A[2][8192] @0, Bg[2][4096] @16384, Bu[2][4096] @24576. Total 64KB -> 2 blk/CU.
__global__ __launch_bounds__(256) void gemm_gateup_pipe(const u16* __restrict__ h2b,
                                                        const u16* __restrict__ gupT,
                                                        u16* __restrict__ act,
                                                        const int* __restrict__ bidx,
                                                        const int* __restrict__ cnt)
{
  extern __shared__ u16 lds[];
  int d = blockIdx.x;
  int e = d & 7, j = d >> 3;
  int y = j / 12, x = j % 12;
  int nc = cnt[e];
  int sr = y*128;
  if(sr >= nc) return;
  const int K = CDIM, NT = K >> 6;
  const u16* Btg = gupT + (size_t)e*1536*CDIM + (size_t)(x*64)*CDIM;
  const u16* Btu = Btg + (size_t)768*CDIM;
  const int* be = bidx + e*CAP;
  int tid = threadIdx.x;
  int lane = tid&63, g = lane>>4, cl = lane&15;
  int w = tid>>6, wr = w>>1, wc = w&1;
  // A staging: 4 chunks/thread (128 rows x 8 slots); B staging: 2 chunks/thread (64 rows x 8 slots)
  int rowA[4], slotA[4], srcA[4];
  long long atok[4];
  #pragma unroll
  for(int l=0;l<4;l++){
    int c = l*256 + tid;
    rowA[l]  = c >> 3;
    slotA[l] = c & 7;
    srcA[l] = (slotA[l] ^ (rowA[l] & 7)) * 8;
    int t = be[sr + rowA[l]];
    if(t < 0 || t >= NTOK) t = 0;
    atok[l] = (long long)t * CDIM;
  }
  int rowB[2], slotB[2], srcB[2];
  #pragma unroll
  for(int l=0;l<2;l++){
    int c = l*256 + tid;
    rowB[l]  = c >> 3;
    slotB[l] = c & 7;
    srcB[l] = (slotB[l] ^ (rowB[l] & 7)) * 8;
  }
  f32x4 accG[4][2], accU[4][2];
  #pragma unroll
  for(int m=0;m<4;m++)
    #pragma unroll
    for(int n=0;n<2;n++){ accG[m][n] = (f32x4){0.f,0.f,0.f,0.f}; accU[m][n] = (f32x4){0.f,0.f,0.f,0.f}; }

  auto stage = [&](int t, int b){
    int k0 = t << 6;
    #pragma unroll
    for(int l=0;l<4;l++)
      GLOAD_LDS16(h2b + atok[l] + k0 + srcA[l],
                  &lds[b*8192 + rowA[l]*64 + slotA[l]*8]);
    #pragma unroll
    for(int l=0;l<2;l++)
      GLOAD_LDS16(Btg + (size_t)rowB[l]*K + k0 + srcB[l],
                  &lds[16384 + b*4096 + rowB[l]*64 + slotB[l]*8]);
    #pragma unroll
    for(int l=0;l<2;l++)
      GLOAD_LDS16(Btu + (size_t)rowB[l]*K + k0 + srcB[l],
                  &lds[24576 + b*4096 + rowB[l]*64 + slotB[l]*8]);
  };

  stage(0, 0);
  for(int t=0;t<NT;t++){
    int buf = t & 1;
    if(t+1 < NT){
      stage(t+1, buf^1);
      asm volatile("s_waitcnt vmcnt(8)" ::: "memory");
    } else {
      asm volatile("s_waitcnt vmcnt(0)" ::: "memory");
    }
    asm volatile("s_barrier" ::: "memory");
    const u16* As_ = &lds[buf*8192];
    const u16* Bg_ = &lds[16384 + buf*4096];
    const u16* Bu_ = &lds[24576 + buf*4096];
    __builtin_amdgcn_s_setprio(1);
    #pragma unroll
    for(int kk=0;kk<2;kk++){
      bf16x8 a[4], bg[2], bu[2];
      #pragma unroll
      for(int m=0;m<4;m++){
        int row = wr*64 + m*16 + cl;
        int sl  = ((4*kk + g) ^ (row & 7)) * 8;
        a[m] = *(const bf16x8*)&As_[row*64 + sl];
      }
      #pragma unroll
      for(int n=0;n<2;n++){
        int row = wc*32 + n*16 + cl;
        int sl  = ((4*kk + g) ^ (row & 7)) * 8;
        bg[n] = *(const bf16x8*)&Bg_[row*64 + sl];
        bu[n] = *(const bf16x8*)&Bu_[row*64 + sl];
      }
      #pragma unroll
      for(int m=0;m<4;m++)
        #pragma unroll
        for(int n=0;n<2;n++){
          accG[m][n] = mfma_bf16(a[m], bg[n], accG[m][n]);
          accU[m][n] = mfma_bf16(a[m], bu[n], accU[m][n]);
        }
    }
    __builtin_amdgcn_s_setprio(0);
    asm volatile("s_barrier" ::: "memory");
  }
  #pragma unroll
  for(int m=0;m<4;m++)
    #pragma unroll
    for(int n=0;n<2;n++)
      #pragma unroll
      for(int jj=0;jj<4;jj++){
        int slot = sr + wr*64 + m*16 + g*4 + jj;
        int col  = x*64 + wc*32 + n*16 + cl;
        float gv = accG[m][n][jj], uv = accU[m][n][jj];
        float av = gv / (1.f + __expf(-gv)) * uv;
        act[((size_t)e*CAP + slot)*FDIM + col] = f2bf(av);
      }
}

// ==== MoE down pipelined 128x128 GEMM, expert->XCD pinned, scatter-atomic ==========
__global__ __launch_bounds__(256) void gemm_down_pipe(const u16* __restrict__ act,
                                                      const u16* __restrict__ downT,
                                                      float* __restrict__ out,
                                                      const int* __restrict__ bidx,
                                                      const float* __restrict__ bw,
                                                      const int* __restrict__ cnt)
{
  extern __shared__ u16 lds[];
  int d = blockIdx.x;
  int e = d & 7, j = d >> 3;
  int y = j >> 4, x = j & 15;
  int nc = cnt[e];
  int sr = y*128;
  if(sr >= nc) return;
  const int K = FDIM, NT = K >> 6;   // 12 steps
  const u16* A  = act   + ((size_t)e*CAP + sr)*FDIM;
  const u16* Bt = downT + (size_t)e*CDIM*FDIM + (size_t)(x*128)*FDIM;
  const int* be = bidx + e*CAP;
  const float* bwe = bw + e*CAP;
  int tid = threadIdx.x;
  int lane = tid&63, g = lane>>4, cl = lane&15;
  int w = tid>>6, wr = w>>1, wc = w&1;
  int rowc[4], slotc[4], srcoff[4];
  #pragma unroll
  for(int l=0;l<4;l++){
    int c = l*256 + tid;
    rowc[l]  = c >> 3;
    slotc[l] = c & 7;
    srcoff[l] = (slotc[l] ^ (rowc[l] & 7)) * 8;
  }
  f32x4 acc[4][4];
  #pragma unroll
  for(int m=0;m<4;m++)
    #pragma unroll
    for(int n=0;n<4;n++) acc[m][n] = (f32x4){0.f,0.f,0.f,0.f};

  auto stage = [&](int t, int b){
    int k0 = t << 6;
    #pragma unroll
    for(int l=0;l<4;l++)
      GLOAD_LDS16(A + (size_t)rowc[l]*K + k0 + srcoff[l],
                  &lds[b*8192 + rowc[l]*64 + slotc[l]*8]);
    #pragma unroll
    for(int l=0;l<4;l++)
      GLOAD_LDS16(Bt + (size_t)rowc[l]*K + k0 + srcoff[l],
                  &lds[16384 + b*8192 + rowc[l]*64 + slotc[l]*8]);
  };

  stage(0, 0);
  for(int t=0;t<NT;t++){
    int buf = t & 1;
    if(t+1 < NT){
      stage(t+1, buf^1);
      asm volatile("s_waitcnt vmcnt(8)" ::: "memory");
    } else {
      asm volatile("s_waitcnt vmcnt(0)" ::: "memory");
    }
    asm volatile("s_barrier" ::: "memory");
    const u16* As_ = &lds[buf*8192];
    const u16* Bs_ = &lds[16384 + buf*8192];
    __builtin_amdgcn_s_setprio(1);
    #pragma unroll
    for(int kk=0;kk<2;kk++){
      bf16x8 a[4], b[4];
      #pragma unroll
      for(int m=0;m<4;m++){
        int row = wr*64 + m*16 + cl;
        int sl  = ((4*kk + g) ^ (row & 7)) * 8;
        a[m] = *(const bf16x8*)&As_[row*64 + sl];
      }
      #pragma unroll
      for(int n=0;n<4;n++){
        int row = wc*64 + n*16 + cl;
        int sl  = ((4*kk + g) ^ (row & 7)) * 8;
        b[n] = *(const bf16x8*)&Bs_[row*64 + sl];
      }
      #pragma unroll
      for(int m=0;m<4;m++)
        #pragma unroll
        for(int n=0;n<4;n++)
          acc[m][n] = mfma_bf16(a[m], b[n], acc[m][n]);
    }
    __builtin_amdgcn_s_setprio(0);
    asm volatile("s_barrier" ::: "memory");
  }
  #pragma unroll
  for(int m=0;m<4;m++)
    #pragma unroll
    for(int jj=0;jj<4;jj++){
      int slot = sr + wr*64 + m*16 + g*4 + jj;
      if(slot < nc){
        int tok = be[slot];
        float wgt = bwe[slot];
        #pragma unroll
        for(int n=0;n<4;n++){
          int col = x*128 + wc*64 + n*16 + cl;
          atomicAdd(out + (size_t)tok*CDIM + col, wgt * acc[m][n][jj]);
        }
      }
    }
}

// ------------------------------------ launch ---------------------------------------
extern "C" void kernel_launch(void* const* d_in, const int* in_sizes, int n_in,
                              void* d_out, int out_size, void* d_ws, size_t ws_size,
                              hipStream_t stream)
{
  const float* x     = (const float*)d_in[0];
  const float* cosb  = (const float*)d_in[1];
  const float* sinb  = (const float*)d_in[2];
  const float* ln1w  = (const float*)d_in[3];
  const float* qw    = (const float*)d_in[4];
  const float* kw    = (const float*)d_in[5];
  const float* vw    = (const float*)d_in[6];
  const float* ow    = (const float*)d_in[7];
  const float* qnw   = (const float*)d_in[8];
  const float* knw   = (const float*)d_in[9];
  const float* ln2w  = (const float*)d_in[10];
  const float* gatew = (const float*)d_in[11];
  const float* gupw  = (const float*)d_in[12];
  const float* downw = (const float*)d_in[13];
  float* out = (float*)d_out;

  char* ws = (char*)d_ws;
  size_t off = 0;
  auto alloc = [&](size_t bytes)->char*{
    char* p = ws + off;
    off = (off + bytes + 255) & ~(size_t)255;
    return p;
  };
  u16*   wqkvT = (u16*)  alloc((size_t)6144*2048*2);
  u16*   owT   = (u16*)  alloc((size_t)2048*4096*2);
  u16*   gupT  = (u16*)  alloc((size_t)8*1536*2048*2);
  u16*   downT = (u16*)  alloc((size_t)8*2048*768*2);
  u16*   h1b   = (u16*)  alloc((size_t)2048*2048*2);
  u16*   qkvb  = (u16*)  alloc((size_t)2048*6144*2);
  u16*   qb    = (u16*)  alloc((size_t)2*32*1024*128*2);
  u16*   kb    = (u16*)  alloc((size_t)2*8*1024*128*2);
  u16*   vt    = (u16*)  alloc((size_t)2*8*1024*128*2);
  u16*   aob   = (u16*)  alloc((size_t)2048*4096*2);
  float* h2f   = (float*)alloc((size_t)2048*2048*4);
  u16*   h2b   = (u16*)  alloc((size_t)2048*2048*2);
  u16*   actb  = (u16*)  alloc((size_t)8*2048*768*2);
  int*   bidx  = (int*)  alloc((size_t)8*2048*4);
  float* bwgt  = (float*)alloc((size_t)8*2048*4);
  float* gwT   = (float*)alloc((size_t)8*2048*4);
  int*   cnt   = (int*)  alloc(64);
  (void)ws_size; (void)in_sizes; (void)n_in; (void)out_size;

  hipMemsetAsync(cnt, 0, 8*sizeof(int), stream);

  // weight transposes/casts (64x64-tile, 16B r/w); q+k+v merged
  cast_transpose_qkv<<<dim3(96,32), 256, 0, stream>>>(qw, kw, vw, wqkvT);
  cast_transpose<<<dim3(32,64,1), 256, 0, stream>>>(ow, owT,      4096, 2048, 2048, 1, 0, 0);
  cast_transpose<<<dim3(24,32,8), 256, 0, stream>>>(gupw, gupT,   2048, 1536, 1536, 8, 0, (long long)2048*1536);
  cast_transpose<<<dim3(32,12,8), 256, 0, stream>>>(downw, downT, 768,  2048, 2048, 8, 0, (long long)768*2048);
  transpose_gate<<<64, 256, 0, stream>>>(gatew, gwT);

  // ln1 + cast
  rmsnorm_kernel<<<2048, 256, 0, stream>>>(x, ln1w, h1b, nullptr);
  // qkv = h @ [q|k|v]  (M=2048, N=6144, K=2048) -> bf16 ; 256x192 pipe, 256 blocks
  gemm256<<<dim3(32,8), 512, 114688, stream>>>(h1b, wqkvT, qkvb, 2048, 6144, 2048);
  // q/k: per-head rmsnorm + rope (+ q*scale) -> bf16
  qk_norm_rope<<<dim3(2048,40), 128, 0, stream>>>(qkvb, cosb, sinb, qnw, knw, qb, kb);
  // v -> (b,kv,D,T) bf16
  transpose_u16<<<dim3(4,32,16), 256, 0, stream>>>(qkvb + 5120, vt, 1024, 128, 6144, 8,
                                                   (long long)1024*6144, 128);
  // attention: paired q-tiles, 8 waves, double-buffered K/V (88064 B LDS)
  attn_kernel<<<dim3(16,8,2), 512, 88064, stream>>>(qb, kb, vt, aob);
  // o-proj + residual -> out  (pipelined 128x128)
  gemm_oproj_pipe<<<256, 256, 65536, stream>>>(aob, owT, out, x, 2048, 2048, 4096);
  // ln2 (fp32 for router + bf16 for experts)
  rmsnorm_kernel<<<2048, 256, 0, stream>>>(out, ln2w, h2b, h2f);
  // routing (fp32 h2f + coalesced gwT)
  route_kernel<<<512, 256, 0, stream>>>(h2f, gwT, cnt, bidx, bwgt);
  // experts: pipelined, expert->XCD pinned; gate_up 128x(64G+64U), 64KB LDS, 2 blk/CU
  gemm_gateup_pipe<<<1536, 256, 65536, stream>>>(h2b, gupT, actb, bidx, cnt);
  gemm_down_pipe<<<2048, 256, 65536, stream>>>(actb, downT, out, bidx, bwgt, cnt);
}